// Round 3
// baseline (10284.819 us; speedup 1.0000x reference)
//
#include <hip/hip_runtime.h>
#include <hip/hip_bf16.h>
#include <hip/hip_cooperative_groups.h>

namespace cg = cooperative_groups;

// Doubly-recurrent LSTM + gumbel-sigmoid gate, B=256,T=64,H=512,V=6207,YF=2048.
// Single persistent cooperative kernel: 256 blocks x 512 threads, grid.sync()
// between recurrence stages (3/step). Split-bf16 (hi+lo) MFMA, fp32 accum.

typedef __attribute__((ext_vector_type(8))) short short8;   // 8 bf16 = 1 MFMA operand
typedef __attribute__((ext_vector_type(4))) float floatx4;  // MFMA accumulator

#define MFMA16(a, b, c) __builtin_amdgcn_mfma_f32_16x16x32_bf16(a, b, c, 0, 0, 0)

__device__ inline float bf2f(ushort u) {
    union { unsigned int u32; float f; } v; v.u32 = ((unsigned int)u) << 16; return v.f;
}
__device__ inline ushort f2bf(float f) {  // RNE, finite inputs only
    union { float f; unsigned int u; } v; v.f = f;
    return (ushort)((v.u + 0x7fffu + ((v.u >> 16) & 1u)) >> 16);
}
__device__ inline short8 ld8(const ushort* p) { return *(const short8*)p; }
__device__ inline float sigf(float x) { return 1.0f / (1.0f + expf(-x)); }
__device__ inline void mm3(floatx4& acc, short8 ah, short8 al, short8 bh, short8 bl) {
    acc = MFMA16(ah, bh, acc);
    acc = MFMA16(ah, bl, acc);
    acc = MFMA16(al, bh, acc);
}

// Pipelined split-bf16 GEMM K-loop: pointers are row bases (window-offset
// already applied); lane k-offset (quad*8) added internally. K multiple of 32.
__device__ inline void gemm_hl(floatx4& acc, const ushort* Ah, const ushort* Al,
                               const ushort* Bh, const ushort* Bl, int K) {
    int q8 = ((threadIdx.x & 63) >> 4) * 8;
    short8 cah = ld8(Ah + q8), cal = ld8(Al + q8);
    short8 cbh = ld8(Bh + q8), cbl = ld8(Bl + q8);
    for (int k0 = 32; k0 <= K; k0 += 32) {
        short8 nah = cah, nal = cal, nbh = cbh, nbl = cbl;
        if (k0 < K) {
            nah = ld8(Ah + k0 + q8); nal = ld8(Al + k0 + q8);
            nbh = ld8(Bh + k0 + q8); nbl = ld8(Bl + k0 + q8);
        }
        mm3(acc, cah, cal, cbh, cbl);
        cah = nah; cal = nal; cbh = nbh; cbl = nbl;
    }
}

struct KP {
    // raw inputs
    const float *y, *emb, *W_ih, *W_hh, *b_ih, *b_hh;
    const float *W_iht, *W_hht, *b_iht, *b_hht, *Wg, *bg, *Wlin, *blin, *u1, *u2;
    const int* x;
    // ws state
    float *c, *ct, *gy, *z3b;
    ushort *h0, *h1, *ht, *hf;
    ushort* wreg;
    // split views into wreg
    const ushort *Wih_hi, *Wih_lo, *Whh_hi, *Whh_lo;
    const ushort *Wiht_hi, *Wiht_lo, *Whht_hi, *Whht_lo;
    const ushort *Wg_hi, *Wg_lo, *Wl_hi, *Wl_lo, *em_hi, *em_lo, *y_hi, *y_lo;
    float* out;
};

__global__ void __launch_bounds__(512, 2) k_all(KP p) {
    cg::grid_group grid = cg::this_grid();
    const int bid = blockIdx.x;           // 0..255
    const int tid = threadIdx.x;          // 0..511
    const int w = tid >> 6;               // wave 0..7
    const int lane = tid & 63;
    const int quad = lane >> 4;
    const int lr = lane & 15;
    const float EPS = 1e-10f;

    __shared__ float smem[2176];

    // ================= prep: zero state + split fp32 -> bf16 hi/lo ==========
    {
        unsigned* zz = (unsigned*)p.c;    // c,ct (1MB f32) then h0,ht (1MB bf16): 2MB
        for (unsigned i = bid * 512u + tid; i < 524288u; i += 131072u) zz[i] = 0u;
        for (unsigned i = bid * 512u + tid; i < 9338368u; i += 131072u) {
            const float* src; ushort* hi; unsigned n, loc;
            if (i < 4194304u) {
                unsigned seg = i >> 20; loc = i & 1048575u; n = 1048576u;
                hi = p.wreg + seg * 2097152u;
                src = (seg == 0) ? p.W_ih : (seg == 1) ? p.W_hh : (seg == 2) ? p.W_iht : p.W_hht;
            } else if (i < 5505024u) { loc = i - 4194304u; src = p.Wg;   hi = p.wreg + 8388608u;  n = 1310720u; }
            else if (i < 5636096u)   { loc = i - 5505024u; src = p.Wlin; hi = p.wreg + 11010048u; n = 131072u; }
            else if (i < 8814080u)   { loc = i - 5636096u; src = p.emb;  hi = p.wreg + 11272192u; n = 3177984u; }
            else                     { loc = i - 8814080u; src = p.y;    hi = p.wreg + 17628160u; n = 524288u; }
            float v = src[loc];
            ushort h = f2bf(v);
            hi[loc] = h;
            hi[n + loc] = f2bf(v - bf2f(h));
        }
    }
    grid.sync();

    // ================= gy = y @ Wg[:,512:].T + bg (K=2048, K-split 4) =======
    {
        int m0 = (bid >> 4) * 16, n0 = (bid & 15) * 32;
        int wn = w & 1, kh = w >> 1;          // K window 512
        int arow = m0 + lr, brow = n0 + wn * 16 + lr;
        floatx4 acc = {};
        gemm_hl(acc, p.y_hi + arow * 2048 + kh * 512, p.y_lo + arow * 2048 + kh * 512,
                p.Wg_hi + brow * 2560 + 512 + kh * 512, p.Wg_lo + brow * 2560 + 512 + kh * 512, 512);
#pragma unroll
        for (int r4 = 0; r4 < 4; r4++)
            smem[kh * 528 + (quad * 4 + r4) * 33 + wn * 16 + lr] = acc[r4];
        __syncthreads();
        int row = tid >> 5, col = tid & 31;
        float s = smem[row * 33 + col] + smem[528 + row * 33 + col] +
                  smem[1056 + row * 33 + col] + smem[1584 + row * 33 + col];
        p.gy[(m0 + row) * 512 + n0 + col] = s + p.bg[n0 + col];
    }
    grid.sync();

    // ================= recurrence ===========================================
    for (int t = 0; t < 64; t++) {
        const ushort* hcur = (t & 1) ? p.h1 : p.h0;
        ushort* hnext = (t & 1) ? p.h0 : p.h1;

        // ---- Stage A: z1 = h@W_hh.T + emb[x_t]@W_ih.T -> LSTM -> c, h_t ----
        //      plus z3b = ht@W_hht.T + b_iht + b_hht
        {
            int m0 = (bid >> 5) * 32, j0 = (bid & 31) * 16;
            int wm = w & 1, wg = w >> 1;      // gate g = wg
            int arow = m0 + wm * 16 + lr;
            int brow = wg * 512 + j0 + lr;
            floatx4 acc = {};
            gemm_hl(acc, hcur + arow * 1024, hcur + arow * 1024 + 512,
                    p.Whh_hi + brow * 512, p.Whh_lo + brow * 512, 512);
            int tok = p.x[arow * 64 + t];
            gemm_hl(acc, p.em_hi + tok * 512, p.em_lo + tok * 512,
                    p.Wih_hi + brow * 512, p.Wih_lo + brow * 512, 512);
            float bias = p.b_ih[brow] + p.b_hh[brow];
#pragma unroll
            for (int r4 = 0; r4 < 4; r4++)
                smem[(wm * 16 + quad * 4 + r4) * 68 + wg * 16 + lr] = acc[r4] + bias;
        }
        __syncthreads();
        {
            int m0 = (bid >> 5) * 32, j0 = (bid & 31) * 16;
            int ml = tid >> 4, jj = tid & 15;
            float zi = smem[ml * 68 + jj],      zf = smem[ml * 68 + 16 + jj];
            float zg = smem[ml * 68 + 32 + jj], zo = smem[ml * 68 + 48 + jj];
            int gi = (m0 + ml) * 512 + j0 + jj;
            float cv = p.c[gi];
            cv = sigf(zf) * cv + sigf(zi) * tanhf(zg);
            p.c[gi] = cv;
            float hv = sigf(zo) * tanhf(cv);
            ushort hb = f2bf(hv);
            hnext[(m0 + ml) * 1024 + j0 + jj] = hb;
            hnext[(m0 + ml) * 1024 + 512 + j0 + jj] = f2bf(hv - bf2f(hb));
        }
        {   // z3b (reads ht of step t-1; no smem use)
            int m0 = (bid >> 5) * 32, bn = bid & 31;
            int wm = w & 1, wn2 = w >> 1;
            int arow = m0 + wm * 16 + lr;
            int brow = bn * 64 + wn2 * 16 + lr;
            floatx4 acc = {};
            gemm_hl(acc, p.ht + arow * 1024, p.ht + arow * 1024 + 512,
                    p.Whht_hi + brow * 512, p.Whht_lo + brow * 512, 512);
            float bias = p.b_iht[brow] + p.b_hht[brow];
#pragma unroll
            for (int r4 = 0; r4 < 4; r4++)
                p.z3b[(m0 + wm * 16 + quad * 4 + r4) * 2048 + brow] = acc[r4] + bias;
        }
        grid.sync();

        // ---- Stage B: gate logits -> hf = h_t * hard_gate (K-split 4) ------
        {
            int m0 = (bid >> 4) * 16, n0 = (bid & 15) * 32;
            int wn = w & 1, kh = w >> 1;      // K window 128
            int arow = m0 + lr, brow = n0 + wn * 16 + lr;
            floatx4 acc = {};
            gemm_hl(acc, hnext + arow * 1024 + kh * 128, hnext + arow * 1024 + 512 + kh * 128,
                    p.Wg_hi + brow * 2560 + kh * 128, p.Wg_lo + brow * 2560 + kh * 128, 128);
#pragma unroll
            for (int r4 = 0; r4 < 4; r4++)
                smem[kh * 528 + (quad * 4 + r4) * 33 + wn * 16 + lr] = acc[r4];
            __syncthreads();
            int row = tid >> 5, col = tid & 31;
            float z2 = smem[row * 33 + col] + smem[528 + row * 33 + col] +
                       smem[1056 + row * 33 + col] + smem[1584 + row * 33 + col];
            int grow = m0 + row, gcol = n0 + col;
            float logit = fmaxf(z2 + p.gy[grow * 512 + gcol], 0.0f);
            float U1 = p.u1[t * 131072 + grow * 512 + gcol];
            float U2 = p.u2[t * 131072 + grow * 512 + gcol];
            float noise = -logf(logf(U2 + EPS) / logf(U1 + EPS) + EPS);
            bool gbit = sigf(logit + noise) >= 0.5f;
            int base = grow * 1024 + gcol;
            p.hf[base] = gbit ? hnext[base] : (ushort)0;
            p.hf[base + 512] = gbit ? hnext[base + 512] : (ushort)0;
        }
        grid.sync();

        // ---- Stage C: z3 = hf@W_iht.T + z3b -> LSTM -> ct, ht --------------
        {
            int m0 = (bid >> 5) * 32, j0 = (bid & 31) * 16;
            int wm = w & 1, wg = w >> 1;
            int arow = m0 + wm * 16 + lr;
            int brow = wg * 512 + j0 + lr;
            floatx4 acc = {};
            gemm_hl(acc, p.hf + arow * 1024, p.hf + arow * 1024 + 512,
                    p.Wiht_hi + brow * 512, p.Wiht_lo + brow * 512, 512);
#pragma unroll
            for (int r4 = 0; r4 < 4; r4++)
                smem[(wm * 16 + quad * 4 + r4) * 68 + wg * 16 + lr] =
                    acc[r4] + p.z3b[(m0 + wm * 16 + quad * 4 + r4) * 2048 + brow];
        }
        __syncthreads();
        {
            int m0 = (bid >> 5) * 32, j0 = (bid & 31) * 16;
            int ml = tid >> 4, jj = tid & 15;
            float zi = smem[ml * 68 + jj],      zf = smem[ml * 68 + 16 + jj];
            float zg = smem[ml * 68 + 32 + jj], zo = smem[ml * 68 + 48 + jj];
            int gi = (m0 + ml) * 512 + j0 + jj;
            float cv = p.ct[gi];
            cv = sigf(zf) * cv + sigf(zi) * tanhf(zg);
            p.ct[gi] = cv;
            float hv = sigf(zo) * tanhf(cv);
            ushort hb = f2bf(hv);
            p.ht[(m0 + ml) * 1024 + j0 + jj] = hb;
            p.ht[(m0 + ml) * 1024 + 512 + j0 + jj] = f2bf(hv - bf2f(hb));
        }
        grid.sync();
    }

    // ================= out = relu(ht @ Wlin.T + blin) (K-split 8) ===========
    {
        int m0 = (bid >> 4) * 16, n0 = (bid & 15) * 16;
        int kh = w;                           // K window 64
        int arow = m0 + lr, brow = n0 + lr;
        floatx4 acc = {};
        gemm_hl(acc, p.ht + arow * 1024 + kh * 64, p.ht + arow * 1024 + 512 + kh * 64,
                p.Wl_hi + brow * 512 + kh * 64, p.Wl_lo + brow * 512 + kh * 64, 64);
#pragma unroll
        for (int r4 = 0; r4 < 4; r4++)
            smem[kh * 272 + (quad * 4 + r4) * 17 + lr] = acc[r4];
        __syncthreads();
        if (tid < 256) {
            int row = tid >> 4, col = tid & 15;
            float s = 0.0f;
#pragma unroll
            for (int k = 0; k < 8; k++) s += smem[k * 272 + row * 17 + col];
            p.out[(m0 + row) * 256 + n0 + col] = fmaxf(s + p.blin[n0 + col], 0.0f);
        }
    }
}

// ---------------------------------------------------------------------------
extern "C" void kernel_launch(void* const* d_in, const int* in_sizes, int n_in,
                              void* d_out, int out_size, void* d_ws, size_t ws_size,
                              hipStream_t stream) {
    (void)in_sizes; (void)n_in; (void)out_size; (void)ws_size;
    KP p;
    p.y     = (const float*)d_in[0];
    p.x     = (const int*)d_in[1];
    p.emb   = (const float*)d_in[2];
    p.W_ih  = (const float*)d_in[3];
    p.W_hh  = (const float*)d_in[4];
    p.b_ih  = (const float*)d_in[5];
    p.b_hh  = (const float*)d_in[6];
    p.W_iht = (const float*)d_in[7];
    p.W_hht = (const float*)d_in[8];
    p.b_iht = (const float*)d_in[9];
    p.b_hht = (const float*)d_in[10];
    p.Wg    = (const float*)d_in[11];
    p.bg    = (const float*)d_in[12];
    p.Wlin  = (const float*)d_in[13];
    p.blin  = (const float*)d_in[14];
    p.u1    = (const float*)d_in[15];
    p.u2    = (const float*)d_in[16];
    p.out   = (float*)d_out;

    // ws layout (f32 units): c[131072] ct[131072] | ushort: h0 ht h1 hf
    // (262144 each) | gy[131072] z3b[524288] | wreg (18676736 ushorts)
    float* wsf = (float*)d_ws;
    p.c  = wsf;
    p.ct = wsf + 131072;
    ushort* us = (ushort*)(wsf + 262144);
    p.h0 = us;
    p.ht = us + 262144;
    p.h1 = us + 524288;
    p.hf = us + 786432;
    p.gy  = wsf + 786432;
    p.z3b = wsf + 917504;
    p.wreg = (ushort*)(wsf + 1441792);
    p.Wih_hi  = p.wreg;             p.Wih_lo  = p.wreg + 1048576;
    p.Whh_hi  = p.wreg + 2097152;   p.Whh_lo  = p.wreg + 3145728;
    p.Wiht_hi = p.wreg + 4194304;   p.Wiht_lo = p.wreg + 5242880;
    p.Whht_hi = p.wreg + 6291456;   p.Whht_lo = p.wreg + 7340032;
    p.Wg_hi   = p.wreg + 8388608;   p.Wg_lo   = p.wreg + 9699328;
    p.Wl_hi   = p.wreg + 11010048;  p.Wl_lo   = p.wreg + 11141120;
    p.em_hi   = p.wreg + 11272192;  p.em_lo   = p.wreg + 14450176;
    p.y_hi    = p.wreg + 17628160;  p.y_lo    = p.wreg + 18152448;

    void* args[] = {(void*)&p};
    hipLaunchCooperativeKernel((const void*)k_all, dim3(256), dim3(512), args, 0, stream);
}

// Round 4
// 4201.213 us; speedup vs baseline: 2.4481x; 2.4481x over previous
//
#include <hip/hip_runtime.h>
#include <hip/hip_bf16.h>

// Doubly-recurrent LSTM + gumbel-sigmoid gate, B=256,T=64,H=512,V=6207,YF=2048.
// Persistent cooperative kernel with LIGHT barriers (atomic counter, no cache
// fences). Weights stay L2-cached (prep kernel + boundary flush); recurrent
// state crosses blocks via device-coherent (AGENT-scope) atomics; c/ct live
// in registers. Split-bf16 (hi+lo) MFMA, fp32 accumulate (gate-flip safe).

typedef __attribute__((ext_vector_type(8))) short short8;   // 8 bf16 = 1 MFMA operand
typedef __attribute__((ext_vector_type(4))) float floatx4;  // MFMA accumulator

#define MFMA16(a, b, c) __builtin_amdgcn_mfma_f32_16x16x32_bf16(a, b, c, 0, 0, 0)
#define AGENT __HIP_MEMORY_SCOPE_AGENT

__device__ inline float bf2f(ushort u) {
    union { unsigned int u32; float f; } v; v.u32 = ((unsigned int)u) << 16; return v.f;
}
__device__ inline ushort f2bf(float f) {  // RNE, finite inputs only
    union { float f; unsigned int u; } v; v.f = f;
    return (ushort)((v.u + 0x7fffu + ((v.u >> 16) & 1u)) >> 16);
}
__device__ inline short8 ld8(const ushort* p) { return *(const short8*)p; }
__device__ inline float sigf(float x) { return 1.0f / (1.0f + expf(-x)); }
__device__ inline void mm3(floatx4& acc, short8 ah, short8 al, short8 bh, short8 bl) {
    acc = MFMA16(ah, bh, acc);
    acc = MFMA16(ah, bl, acc);
    acc = MFMA16(al, bh, acc);
}

// ---------------------------------------------------------------------------
// prep: split fp32 arrays into bf16 hi/lo in wreg; zero hP0, htP, barrier.
// ---------------------------------------------------------------------------
__global__ __launch_bounds__(256) void k_prep(const float* __restrict__ w0,
                                              const float* __restrict__ w1,
                                              const float* __restrict__ w2,
                                              const float* __restrict__ w3,
                                              const float* __restrict__ wg,
                                              const float* __restrict__ wl,
                                              const float* __restrict__ em,
                                              const float* __restrict__ yy,
                                              ushort* __restrict__ wreg,
                                              uint* __restrict__ hP0,
                                              uint* __restrict__ htP,
                                              uint* __restrict__ bar) {
    unsigned i = blockIdx.x * 256u + threadIdx.x;
    if (i >= 9600576u) return;
    if (i >= 9338368u) {
        unsigned z = i - 9338368u;
        if (z < 131072u) hP0[z] = 0u;
        else if (z < 262144u) htP[z - 131072u] = 0u;
        else bar[z - 262144u] = 0u;
        return;
    }
    const float* src; ushort* hi; unsigned n, loc;
    if (i < 4194304u) {
        unsigned seg = i >> 20; loc = i & 1048575u; n = 1048576u;
        hi = wreg + seg * 2097152u;
        src = (seg == 0) ? w0 : (seg == 1) ? w1 : (seg == 2) ? w2 : w3;
    } else if (i < 5505024u) { loc = i - 4194304u; src = wg; hi = wreg + 8388608u;  n = 1310720u; }
    else if (i < 5636096u)   { loc = i - 5505024u; src = wl; hi = wreg + 11010048u; n = 131072u; }
    else if (i < 8814080u)   { loc = i - 5636096u; src = em; hi = wreg + 11272192u; n = 3177984u; }
    else                     { loc = i - 8814080u; src = yy; hi = wreg + 17628160u; n = 524288u; }
    float v = src[loc];
    ushort h = f2bf(v);
    hi[loc] = h;
    hi[n + loc] = f2bf(v - bf2f(h));
}

// ---------------------------------------------------------------------------
// gy = y @ Wg[:,512:].T + bg  (M=256,N=512,K=2048; 256 blocks, 4-way K-split)
// ---------------------------------------------------------------------------
__global__ __launch_bounds__(512) void k_gy(const ushort* __restrict__ y_hi,
                                            const ushort* __restrict__ y_lo,
                                            const ushort* __restrict__ Wg_hi,
                                            const ushort* __restrict__ Wg_lo,
                                            const float* __restrict__ bg,
                                            float* __restrict__ gy) {
    __shared__ float zsB[4 * 528];
    int tid = threadIdx.x, lane = tid & 63, w = tid >> 6;
    int quad = lane >> 4, lr = lane & 15, q8 = quad * 8;
    int r0 = (blockIdx.x >> 4) * 16, n0 = (blockIdx.x & 15) * 32;
    int nh = w & 1, kq = w >> 1;
    int arow = r0 + lr, brow = n0 + nh * 16 + lr;
    floatx4 acc = {};
#pragma unroll
    for (int k0 = 0; k0 < 512; k0 += 32) {
        short8 ah = ld8(y_hi + arow * 2048 + kq * 512 + k0 + q8);
        short8 al = ld8(y_lo + arow * 2048 + kq * 512 + k0 + q8);
        short8 bh = ld8(Wg_hi + brow * 2560 + 512 + kq * 512 + k0 + q8);
        short8 bl = ld8(Wg_lo + brow * 2560 + 512 + kq * 512 + k0 + q8);
        mm3(acc, ah, al, bh, bl);
    }
#pragma unroll
    for (int r4 = 0; r4 < 4; r4++)
        zsB[kq * 528 + (quad * 4 + r4) * 33 + nh * 16 + lr] = acc[r4];
    __syncthreads();
    int ml = tid >> 5, jj = tid & 31;
    float s = zsB[ml * 33 + jj] + zsB[528 + ml * 33 + jj] +
              zsB[1056 + ml * 33 + jj] + zsB[1584 + ml * 33 + jj];
    gy[(r0 + ml) * 512 + n0 + jj] = s + bg[n0 + jj];
}

// ---------------------------------------------------------------------------
struct KP {
    const float *b_ih, *b_hh, *b_iht, *b_hht, *u1, *u2;
    const int* x;
    uint *cnt, *gen, *hP0, *hP1, *htP, *hfP;
    float *z3b, *gy;
    ushort *ht_hi, *ht_lo;
    const ushort *Whh_hi, *Whh_lo, *Wih_hi, *Wih_lo;
    const ushort *Wiht_hi, *Wiht_lo, *Whht_hi, *Whht_lo;
    const ushort *Wg_hi, *Wg_lo, *em_hi, *em_lo;
};

// Light device barrier: monotonic counter + generation flag, no cache fences.
// The preceding __syncthreads() drains vmcnt(0) so coherent stores are
// globally visible before arrival.
__device__ inline void gbar(uint* cnt, uint* gen, int g) {
    __syncthreads();
    if (threadIdx.x == 0) {
        uint old = __hip_atomic_fetch_add(cnt, 1u, __ATOMIC_RELAXED, AGENT);
        if (old == (uint)g * 256u - 1u) {
            __hip_atomic_store(gen, (uint)g, __ATOMIC_RELAXED, AGENT);
        } else {
            while (__hip_atomic_load(gen, __ATOMIC_RELAXED, AGENT) < (uint)g)
                __builtin_amdgcn_s_sleep(2);
        }
    }
    __syncthreads();
}

// Stage 16 rows of a packed (hi|lo<<16) [256][512] buffer into LDS:
// hi at As[r*1032 + c], lo at As[r*1032 + 520 + c]  (c = 0..511).
__device__ inline void stage_rows(const uint* __restrict__ src, int r0,
                                  ushort* __restrict__ As) {
    int tid = threadIdx.x;
    int sr = tid >> 5, scol = (tid & 31) * 16;
    const unsigned long long* p =
        (const unsigned long long*)(src + (r0 + sr) * 512 + scol);
    ushort* dst = As + sr * 1032;
#pragma unroll
    for (int i = 0; i < 8; i++) {
        unsigned long long v = __hip_atomic_load(p + i, __ATOMIC_RELAXED, AGENT);
        uint u0 = (uint)v, u1v = (uint)(v >> 32);
        int c = scol + i * 2;
        *(uint*)(dst + c) = (u0 & 0xffffu) | ((u1v & 0xffffu) << 16);
        *(uint*)(dst + 520 + c) = (u0 >> 16) | (u1v & 0xffff0000u);
    }
}

__device__ inline short8 fragA(const ushort* As, int row, int k) {
    return *(const short8*)(As + row * 1032 + k);
}

__global__ void __launch_bounds__(512, 1) k_main(KP p) {
    __shared__ ushort As[16 * 1032];
    __shared__ ushort Az[16 * 1032];
    __shared__ float zs[16 * 132];   // also viewed as [4][16][33] in stage B

    const int bid = blockIdx.x;           // 0..255
    const int tid = threadIdx.x;          // 0..511
    const int w = tid >> 6;               // wave 0..7
    const int lane = tid & 63;
    const int quad = lane >> 4;
    const int lr = lane & 15;
    const int q8 = quad * 8;
    const float EPS = 1e-10f;

    const int g16 = bid >> 4;             // row group 0..15
    const int jb = bid & 15;              // col slice 0..15
    const int r0 = g16 * 16;              // 16 batch rows
    const int j0 = jb * 32;               // 32 hidden cols

    // stage A/C wave tile: gate = w>>1, half = w&1
    const int gate = w >> 1, nh = w & 1;
    const int brow = gate * 512 + j0 + nh * 16 + lr;
    // epilogue element per thread
    const int ml = tid >> 5, jj = tid & 31;

    float c_reg = 0.0f, ct_reg = 0.0f;
    int bi = 0;

    for (int t = 0; t < 64; t++) {
        const uint* hcurP = (t & 1) ? p.hP1 : p.hP0;
        uint* hnextP = (t & 1) ? p.hP0 : p.hP1;

        // ======== Stage A: z1 = h@Whh.T + emb@Wih.T -> c,h  |  z3b = ht@Whht.T
        stage_rows(hcurP, r0, As);
        stage_rows(p.htP, r0, Az);
        __syncthreads();
        {
            floatx4 acc = {};
            const ushort* Bh = p.Whh_hi + brow * 512;
            const ushort* Bl = p.Whh_lo + brow * 512;
#pragma unroll
            for (int k0 = 0; k0 < 512; k0 += 32)
                mm3(acc, fragA(As, lr, k0 + q8), fragA(As, lr, 520 + k0 + q8),
                    ld8(Bh + k0 + q8), ld8(Bl + k0 + q8));
            int tok = p.x[(r0 + lr) * 64 + t];
            const ushort* Eh = p.em_hi + (size_t)tok * 512;
            const ushort* El = p.em_lo + (size_t)tok * 512;
            const ushort* B2h = p.Wih_hi + brow * 512;
            const ushort* B2l = p.Wih_lo + brow * 512;
#pragma unroll
            for (int k0 = 0; k0 < 512; k0 += 32)
                mm3(acc, ld8(Eh + k0 + q8), ld8(El + k0 + q8),
                    ld8(B2h + k0 + q8), ld8(B2l + k0 + q8));
            float bias = p.b_ih[brow] + p.b_hh[brow];
#pragma unroll
            for (int r4 = 0; r4 < 4; r4++)
                zs[(quad * 4 + r4) * 132 + gate * 32 + nh * 16 + lr] = acc[r4] + bias;

            // z3b gemm (independent of zs; uses Az)
            floatx4 acc2 = {};
            const ushort* B3h = p.Whht_hi + brow * 512;
            const ushort* B3l = p.Whht_lo + brow * 512;
#pragma unroll
            for (int k0 = 0; k0 < 512; k0 += 32)
                mm3(acc2, fragA(Az, lr, k0 + q8), fragA(Az, lr, 520 + k0 + q8),
                    ld8(B3h + k0 + q8), ld8(B3l + k0 + q8));
            float bias2 = p.b_iht[brow] + p.b_hht[brow];
#pragma unroll
            for (int r4 = 0; r4 < 4; r4++)
                __hip_atomic_store((uint*)&p.z3b[(r0 + quad * 4 + r4) * 2048 + brow],
                                   __float_as_uint(acc2[r4] + bias2),
                                   __ATOMIC_RELAXED, AGENT);
        }
        __syncthreads();
        {
            float zi = zs[ml * 132 + jj],      zf = zs[ml * 132 + 32 + jj];
            float zg = zs[ml * 132 + 64 + jj], zo = zs[ml * 132 + 96 + jj];
            c_reg = sigf(zf) * c_reg + sigf(zi) * tanhf(zg);
            float hv = sigf(zo) * tanhf(c_reg);
            ushort hb = f2bf(hv);
            ushort lb = f2bf(hv - bf2f(hb));
            __hip_atomic_store(&hnextP[(r0 + ml) * 512 + j0 + jj],
                               (uint)hb | ((uint)lb << 16), __ATOMIC_RELAXED, AGENT);
        }
        gbar(p.cnt, p.gen, ++bi);

        // ======== Stage B: gate logits -> hf = h * hard_gate (4-way K-split)
        {
            int n0 = jb * 32;   // same (g16, jb) mapping; n0 == j0
            stage_rows(hnextP, r0, As);
            __syncthreads();
            int kq = w >> 1;
            int brow2 = n0 + nh * 16 + lr;
            floatx4 acc = {};
            const ushort* Bh = p.Wg_hi + brow2 * 2560 + kq * 128;
            const ushort* Bl = p.Wg_lo + brow2 * 2560 + kq * 128;
#pragma unroll
            for (int k0 = 0; k0 < 128; k0 += 32)
                mm3(acc, fragA(As, lr, kq * 128 + k0 + q8),
                    fragA(As, lr, 520 + kq * 128 + k0 + q8),
                    ld8(Bh + k0 + q8), ld8(Bl + k0 + q8));
#pragma unroll
            for (int r4 = 0; r4 < 4; r4++)
                zs[kq * 528 + (quad * 4 + r4) * 33 + nh * 16 + lr] = acc[r4];
            __syncthreads();
            float z2 = zs[ml * 33 + jj] + zs[528 + ml * 33 + jj] +
                       zs[1056 + ml * 33 + jj] + zs[1584 + ml * 33 + jj];
            int grow = r0 + ml, gcol = n0 + jj;
            float logit = fmaxf(z2 + p.gy[grow * 512 + gcol], 0.0f);
            float U1 = __builtin_nontemporal_load(&p.u1[t * 131072 + grow * 512 + gcol]);
            float U2 = __builtin_nontemporal_load(&p.u2[t * 131072 + grow * 512 + gcol]);
            float noise = -logf(logf(U2 + EPS) / logf(U1 + EPS) + EPS);
            bool gbit = sigf(logit + noise) >= 0.5f;
            ushort hb = As[ml * 1032 + gcol];
            ushort lb = As[ml * 1032 + 520 + gcol];
            uint pk = gbit ? ((uint)hb | ((uint)lb << 16)) : 0u;
            __hip_atomic_store(&p.hfP[grow * 512 + gcol], pk, __ATOMIC_RELAXED, AGENT);
        }
        gbar(p.cnt, p.gen, ++bi);

        // ======== Stage C: z3 = hf@Wiht.T + z3b -> ct, ht
        stage_rows(p.hfP, r0, As);
        __syncthreads();
        {
            floatx4 acc = {};
            const ushort* Bh = p.Wiht_hi + brow * 512;
            const ushort* Bl = p.Wiht_lo + brow * 512;
#pragma unroll
            for (int k0 = 0; k0 < 512; k0 += 32)
                mm3(acc, fragA(As, lr, k0 + q8), fragA(As, lr, 520 + k0 + q8),
                    ld8(Bh + k0 + q8), ld8(Bl + k0 + q8));
#pragma unroll
            for (int r4 = 0; r4 < 4; r4++) {
                float zb = __uint_as_float(__hip_atomic_load(
                    (uint*)&p.z3b[(r0 + quad * 4 + r4) * 2048 + brow],
                    __ATOMIC_RELAXED, AGENT));
                zs[(quad * 4 + r4) * 132 + gate * 32 + nh * 16 + lr] = acc[r4] + zb;
            }
        }
        __syncthreads();
        {
            float zi = zs[ml * 132 + jj],      zf = zs[ml * 132 + 32 + jj];
            float zg = zs[ml * 132 + 64 + jj], zo = zs[ml * 132 + 96 + jj];
            ct_reg = sigf(zf) * ct_reg + sigf(zi) * tanhf(zg);
            float hv = sigf(zo) * tanhf(ct_reg);
            ushort hb = f2bf(hv);
            ushort lb = f2bf(hv - bf2f(hb));
            int idx = (r0 + ml) * 512 + j0 + jj;
            __hip_atomic_store(&p.htP[idx], (uint)hb | ((uint)lb << 16),
                               __ATOMIC_RELAXED, AGENT);
            p.ht_hi[idx] = hb;   // normal stores; flushed at kernel end for k_final
            p.ht_lo[idx] = lb;
        }
        gbar(p.cnt, p.gen, ++bi);
    }
}

// ---------------------------------------------------------------------------
// out = relu(ht @ Wlin.T + blin)  (M=256,N=256,K=512 hi/lo) -> fp32
// ---------------------------------------------------------------------------
__global__ __launch_bounds__(256) void k_final(const ushort* __restrict__ ht_hi,
                                               const ushort* __restrict__ ht_lo,
                                               const ushort* __restrict__ Wl_hi,
                                               const ushort* __restrict__ Wl_lo,
                                               const float* __restrict__ blin,
                                               float* __restrict__ out) {
    int tid = threadIdx.x, lane = tid & 63, w = tid >> 6;
    int wm = w & 1, wn = w >> 1, quad = lane >> 4, lr = lane & 15;
    int m0 = blockIdx.y * 64, n0 = blockIdx.x * 64;
    floatx4 acc[2][2] = {};
    for (int k0 = 0; k0 < 512; k0 += 32) {
        short8 ah[2], al[2], bh[2], bl[2];
#pragma unroll
        for (int tn = 0; tn < 2; tn++) {
            int n = n0 + wn * 32 + tn * 16 + lr;
            bh[tn] = ld8(Wl_hi + n * 512 + k0 + quad * 8);
            bl[tn] = ld8(Wl_lo + n * 512 + k0 + quad * 8);
        }
#pragma unroll
        for (int tm = 0; tm < 2; tm++) {
            int r = m0 + wm * 32 + tm * 16 + lr;
            ah[tm] = ld8(ht_hi + r * 512 + k0 + quad * 8);
            al[tm] = ld8(ht_lo + r * 512 + k0 + quad * 8);
        }
#pragma unroll
        for (int tm = 0; tm < 2; tm++)
#pragma unroll
            for (int tn = 0; tn < 2; tn++) mm3(acc[tm][tn], ah[tm], al[tm], bh[tn], bl[tn]);
    }
#pragma unroll
    for (int tm = 0; tm < 2; tm++)
#pragma unroll
        for (int tn = 0; tn < 2; tn++)
#pragma unroll
            for (int r4 = 0; r4 < 4; r4++) {
                int row = m0 + wm * 32 + tm * 16 + quad * 4 + r4;
                int n = n0 + wn * 32 + tn * 16 + lr;
                out[row * 256 + n] = fmaxf(acc[tm][tn][r4] + blin[n], 0.0f);
            }
}

// ---------------------------------------------------------------------------
extern "C" void kernel_launch(void* const* d_in, const int* in_sizes, int n_in,
                              void* d_out, int out_size, void* d_ws, size_t ws_size,
                              hipStream_t stream) {
    (void)in_sizes; (void)n_in; (void)out_size; (void)ws_size;
    const float* y      = (const float*)d_in[0];
    const int*   x      = (const int*)d_in[1];
    const float* emb    = (const float*)d_in[2];
    const float* W_ih   = (const float*)d_in[3];
    const float* W_hh   = (const float*)d_in[4];
    const float* b_ih   = (const float*)d_in[5];
    const float* b_hh   = (const float*)d_in[6];
    const float* W_iht  = (const float*)d_in[7];
    const float* W_hht  = (const float*)d_in[8];
    const float* b_iht  = (const float*)d_in[9];
    const float* b_hht  = (const float*)d_in[10];
    const float* Wg     = (const float*)d_in[11];
    const float* bg     = (const float*)d_in[12];
    const float* Wlin   = (const float*)d_in[13];
    const float* blin   = (const float*)d_in[14];
    const float* u1     = (const float*)d_in[15];
    const float* u2     = (const float*)d_in[16];
    float* out = (float*)d_out;

    // ws layout
    uint*  bar  = (uint*)d_ws;                 // 64 uints (cnt=[0], gen=[1])
    uint*  hP0  = bar + 64;                    // 131072 each, packed hi|lo<<16
    uint*  hP1  = hP0 + 131072;
    uint*  htP  = hP1 + 131072;
    uint*  hfP  = htP + 131072;
    float* z3b  = (float*)(hfP + 131072);      // 256 x 2048 fp32
    float* gy   = z3b + 524288;                // 256 x 512 fp32
    ushort* ht_hi = (ushort*)(gy + 131072);    // 131072
    ushort* ht_lo = ht_hi + 131072;            // 131072
    ushort* wreg  = ht_lo + 131072;            // 18676736 ushorts

    KP p;
    p.b_ih = b_ih; p.b_hh = b_hh; p.b_iht = b_iht; p.b_hht = b_hht;
    p.u1 = u1; p.u2 = u2; p.x = x;
    p.cnt = &bar[0]; p.gen = &bar[1];
    p.hP0 = hP0; p.hP1 = hP1; p.htP = htP; p.hfP = hfP;
    p.z3b = z3b; p.gy = gy; p.ht_hi = ht_hi; p.ht_lo = ht_lo;
    p.Wih_hi  = wreg;             p.Wih_lo  = wreg + 1048576;
    p.Whh_hi  = wreg + 2097152;   p.Whh_lo  = wreg + 3145728;
    p.Wiht_hi = wreg + 4194304;   p.Wiht_lo = wreg + 5242880;
    p.Whht_hi = wreg + 6291456;   p.Whht_lo = wreg + 7340032;
    p.Wg_hi   = wreg + 8388608;   p.Wg_lo   = wreg + 9699328;
    p.em_hi   = wreg + 11272192;  p.em_lo   = wreg + 14450176;
    const ushort* Wl_hi = wreg + 11010048; const ushort* Wl_lo = wreg + 11141120;
    const ushort* y_hi  = wreg + 17628160; const ushort* y_lo  = wreg + 18152448;

    k_prep<<<dim3(37503), dim3(256), 0, stream>>>(W_ih, W_hh, W_iht, W_hht, Wg, Wlin,
                                                  emb, y, wreg, hP0, htP, bar);
    k_gy<<<dim3(256), dim3(512), 0, stream>>>(y_hi, y_lo, p.Wg_hi, p.Wg_lo, bg, gy);

    void* args[] = {(void*)&p};
    hipLaunchCooperativeKernel((const void*)k_main, dim3(256), dim3(512), args, 0, stream);

    k_final<<<dim3(4, 4), dim3(256), 0, stream>>>(ht_hi, ht_lo, Wl_hi, Wl_lo, blin, out);
}

// Round 5
// 3499.828 us; speedup vs baseline: 2.9387x; 1.2004x over previous
//
#include <hip/hip_runtime.h>
#include <hip/hip_bf16.h>

// Doubly-recurrent LSTM + gumbel-sigmoid gate, B=256,T=64,H=512,V=6207,YF=2048.
// Persistent kernel, 3 light barriers/step (hierarchical wave-level arrival,
// single poller, work overlapped into the wait). Split-bf16 (hi+lo) MFMA,
// fp32 accumulate. State crosses blocks via AGENT-scope relaxed atomics;
// weights stay normally cached (written only by prep kernel).

typedef __attribute__((ext_vector_type(8))) short short8;   // 8 bf16 = 1 MFMA operand
typedef __attribute__((ext_vector_type(4))) float floatx4;  // MFMA accumulator

#define MFMA16(a, b, c) __builtin_amdgcn_mfma_f32_16x16x32_bf16(a, b, c, 0, 0, 0)
#define AGENT __HIP_MEMORY_SCOPE_AGENT

__device__ inline float bf2f(ushort u) {
    union { unsigned int u32; float f; } v; v.u32 = ((unsigned int)u) << 16; return v.f;
}
__device__ inline ushort f2bf(float f) {  // RNE, finite inputs only
    union { float f; unsigned int u; } v; v.f = f;
    return (ushort)((v.u + 0x7fffu + ((v.u >> 16) & 1u)) >> 16);
}
__device__ inline short8 ld8(const ushort* p) { return *(const short8*)p; }
__device__ inline float sigf(float x) { return 1.0f / (1.0f + expf(-x)); }
__device__ inline void mm3(floatx4& acc, short8 ah, short8 al, short8 bh, short8 bl) {
    acc = MFMA16(ah, bh, acc);
    acc = MFMA16(ah, bl, acc);
    acc = MFMA16(al, bh, acc);
}

// ---------------------------------------------------------------------------
// prep: split fp32 arrays into bf16 hi/lo in wreg; zero barrier + state.
// ---------------------------------------------------------------------------
__global__ __launch_bounds__(256) void k_prep(const float* __restrict__ w0,
                                              const float* __restrict__ w1,
                                              const float* __restrict__ w2,
                                              const float* __restrict__ w3,
                                              const float* __restrict__ wg,
                                              const float* __restrict__ wl,
                                              const float* __restrict__ em,
                                              const float* __restrict__ yy,
                                              ushort* __restrict__ wreg,
                                              uint* __restrict__ zbase) {
    unsigned i = blockIdx.x * 256u + threadIdx.x;
    if (i >= 9735712u) return;
    if (i >= 9338368u) {           // zero bar(4128) + hP + htP0 + htP1 (393216)
        zbase[i - 9338368u] = 0u;
        return;
    }
    const float* src; ushort* hi; unsigned n, loc;
    if (i < 4194304u) {
        unsigned seg = i >> 20; loc = i & 1048575u; n = 1048576u;
        hi = wreg + seg * 2097152u;
        src = (seg == 0) ? w0 : (seg == 1) ? w1 : (seg == 2) ? w2 : w3;
    } else if (i < 5505024u) { loc = i - 4194304u; src = wg; hi = wreg + 8388608u;  n = 1310720u; }
    else if (i < 5636096u)   { loc = i - 5505024u; src = wl; hi = wreg + 11010048u; n = 131072u; }
    else if (i < 8814080u)   { loc = i - 5636096u; src = em; hi = wreg + 11272192u; n = 3177984u; }
    else                     { loc = i - 8814080u; src = yy; hi = wreg + 17628160u; n = 524288u; }
    float v = src[loc];
    ushort h = f2bf(v);
    hi[loc] = h;
    hi[n + loc] = f2bf(v - bf2f(h));
}

// ---------------------------------------------------------------------------
// gy = y @ Wg[:,512:].T + bg  (M=256,N=512,K=2048; 256 blocks, 4-way K-split)
// ---------------------------------------------------------------------------
__global__ __launch_bounds__(512) void k_gy(const ushort* __restrict__ y_hi,
                                            const ushort* __restrict__ y_lo,
                                            const ushort* __restrict__ Wg_hi,
                                            const ushort* __restrict__ Wg_lo,
                                            const float* __restrict__ bg,
                                            float* __restrict__ gy) {
    __shared__ float zsB[4 * 528];
    int tid = threadIdx.x, lane = tid & 63, w = tid >> 6;
    int quad = lane >> 4, lr = lane & 15, q8 = quad * 8;
    int r0 = (blockIdx.x >> 4) * 16, n0 = (blockIdx.x & 15) * 32;
    int nh = w & 1, kq = w >> 1;
    int arow = r0 + lr, brow = n0 + nh * 16 + lr;
    floatx4 acc = {};
#pragma unroll
    for (int k0 = 0; k0 < 512; k0 += 32) {
        short8 ah = ld8(y_hi + arow * 2048 + kq * 512 + k0 + q8);
        short8 al = ld8(y_lo + arow * 2048 + kq * 512 + k0 + q8);
        short8 bh = ld8(Wg_hi + brow * 2560 + 512 + kq * 512 + k0 + q8);
        short8 bl = ld8(Wg_lo + brow * 2560 + 512 + kq * 512 + k0 + q8);
        mm3(acc, ah, al, bh, bl);
    }
#pragma unroll
    for (int r4 = 0; r4 < 4; r4++)
        zsB[kq * 528 + (quad * 4 + r4) * 33 + nh * 16 + lr] = acc[r4];
    __syncthreads();
    int ml = tid >> 5, jj = tid & 31;
    float s = zsB[ml * 33 + jj] + zsB[528 + ml * 33 + jj] +
              zsB[1056 + ml * 33 + jj] + zsB[1584 + ml * 33 + jj];
    gy[(r0 + ml) * 512 + n0 + jj] = s + bg[n0 + jj];
}

// ---------------------------------------------------------------------------
struct KP {
    const float *b_ih, *b_hh, *b_iht, *b_hht, *u1, *u2, *gy;
    const int* x;
    uint *cnt, *gen, *bcnt;
    uint *hP, *htP0, *htP1, *hfP;
    ushort *ht_hi, *ht_lo;
    const ushort *Whh_hi, *Whh_lo, *Wih_hi, *Wih_lo;
    const ushort *Wiht_hi, *Wiht_lo, *Whht_hi, *Whht_lo;
    const ushort *Wg_hi, *Wg_lo, *em_hi, *em_lo;
};

// Hierarchical split-phase barrier. arrive: drain own stores, bump per-block
// counter; last wave of block bumps global counter; last block flips gen.
// Caller does overlap-work between arrive and wait.
__device__ inline int bar_arrive(uint* bcl, uint* cnt, uint* gen, uint g) {
    __builtin_amdgcn_s_waitcnt(0);
    asm volatile("" ::: "memory");
    int ip = 0;
    if ((threadIdx.x & 63) == 0) {
        uint o = __hip_atomic_fetch_add(bcl, 1u, __ATOMIC_RELAXED, AGENT);
        if (o == 8u * g - 1u) {
            ip = 1;
            uint o2 = __hip_atomic_fetch_add(cnt, 1u, __ATOMIC_RELAXED, AGENT);
            if (o2 == 256u * g - 1u)
                __hip_atomic_store(gen, g, __ATOMIC_RELAXED, AGENT);
        }
    }
    return __shfl(ip, 0);
}
__device__ inline void bar_wait(uint* gen, uint g, int ip) {
    if (ip && (threadIdx.x & 63) == 0) {
        while (__hip_atomic_load(gen, __ATOMIC_RELAXED, AGENT) < g)
            __builtin_amdgcn_s_sleep(1);
    }
    __syncthreads();
}

// Stage 16 rows of a packed (hi|lo<<16) [256][512] buffer into LDS:
// hi at dst[r*1032 + c], lo at dst[r*1032 + 520 + c].
__device__ inline void stage_state(const uint* __restrict__ src, int r0,
                                   ushort* __restrict__ dst) {
    int tid = threadIdx.x;
    int sr = tid >> 5, scol = (tid & 31) * 16;
    const unsigned long long* p =
        (const unsigned long long*)(src + (r0 + sr) * 512 + scol);
    ushort* d = dst + sr * 1032;
#pragma unroll
    for (int i = 0; i < 8; i++) {
        unsigned long long v = __hip_atomic_load(p + i, __ATOMIC_RELAXED, AGENT);
        uint u0 = (uint)v, u1v = (uint)(v >> 32);
        int c = scol + i * 2;
        *(uint*)(d + c) = (u0 & 0xffffu) | ((u1v & 0xffffu) << 16);
        *(uint*)(d + 520 + c) = (u0 >> 16) | (u1v & 0xffff0000u);
    }
}

// Stage 16 emb rows (hi/lo planes, plain cached loads) into LDS, As layout.
__device__ inline void stage_emb(const ushort* __restrict__ emh,
                                 const ushort* __restrict__ eml,
                                 const int* __restrict__ x, int r0, int t,
                                 ushort* __restrict__ dst) {
    int tid = threadIdx.x;
    int sr = tid >> 5, sc = (tid & 31) * 16;
    int tok = x[(r0 + sr) * 64 + t];
    const short8* ph = (const short8*)(emh + (size_t)tok * 512 + sc);
    const short8* pl = (const short8*)(eml + (size_t)tok * 512 + sc);
    short8 h0 = ph[0], h1 = ph[1], l0 = pl[0], l1 = pl[1];
    ushort* d = dst + sr * 1032;
    *(short8*)(d + sc) = h0;       *(short8*)(d + sc + 8) = h1;
    *(short8*)(d + 520 + sc) = l0; *(short8*)(d + 520 + sc + 8) = l1;
}

__device__ inline short8 fragA(const ushort* As, int row, int k) {
    return *(const short8*)(As + row * 1032 + k);
}

__global__ void __launch_bounds__(512, 1) k_main(KP p) {
    __shared__ ushort As[16 * 1032];   // h tile (stage B stages h_t; stage A(t+1) reuses)
    __shared__ ushort Ae[16 * 1032];   // emb rows for current t (staged during bar-C wait)
    __shared__ ushort Az[16 * 1032];   // ht(t-1) tile (staged during bar-B wait)
    __shared__ ushort Ac[16 * 1032];   // hf tile
    __shared__ float zs[16 * 132];     // stage A/C epilogue; B K-split partials

    const int bid = blockIdx.x;            // 0..255
    const int tid = threadIdx.x;           // 0..511
    const int w = tid >> 6;                // wave 0..7
    const int lane = tid & 63;
    const int quad = lane >> 4;
    const int lr = lane & 15;
    const int q8 = quad * 8;
    const float EPS = 1e-10f;

    const int g16 = bid >> 4, jb = bid & 15;
    const int r0 = g16 * 16, j0 = jb * 32;
    const int gate = w >> 1, nh = w & 1;
    const int brow = gate * 512 + j0 + nh * 16 + lr;   // stage A/C weight row
    const int kq = w >> 1;                              // stage B K-split window
    const int browB = j0 + nh * 16 + lr;                // stage B Wg row
    const int ml = tid >> 5, jj = tid & 31;             // epilogue element

    // hoisted loop-invariants
    const float biasA = p.b_ih[brow] + p.b_hh[brow];
    const float biasC = p.b_iht[brow] + p.b_hht[brow];
    const float gy_r = p.gy[(r0 + ml) * 512 + j0 + jj];
    const ushort* WhhH = p.Whh_hi + brow * 512;
    const ushort* WhhL = p.Whh_lo + brow * 512;
    const ushort* WihH = p.Wih_hi + brow * 512;
    const ushort* WihL = p.Wih_lo + brow * 512;
    const ushort* WitH = p.Wiht_hi + brow * 512;
    const ushort* WitL = p.Wiht_lo + brow * 512;
    const ushort* WhtH = p.Whht_hi + brow * 512;
    const ushort* WhtL = p.Whht_lo + brow * 512;
    const ushort* WgH = p.Wg_hi + browB * 2560 + kq * 128;
    const ushort* WgL = p.Wg_lo + browB * 2560 + kq * 128;
    const float* pu1 = p.u1 + (r0 + ml) * 512 + j0 + jj;
    const float* pu2 = p.u2 + (r0 + ml) * 512 + j0 + jj;
    uint* bcl = p.bcnt + bid * 16;

    // init: h(-1) = 0 in As; emb rows for t=0 into Ae
    for (int i = tid; i < 16 * 1032; i += 512) As[i] = 0;
    stage_emb(p.em_hi, p.em_lo, p.x, r0, 0, Ae);
    __syncthreads();

    float c_reg = 0.0f, ct_reg = 0.0f;
    uint g = 0;

    for (int t = 0; t < 64; t++) {
        // ==== Stage A: z1 = h@Whh.T + emb@Wih.T -> c, h ======================
        {
            floatx4 a1 = {}, a2 = {};
#pragma unroll
            for (int k0 = 0; k0 < 512; k0 += 32) {
                mm3(a1, fragA(As, lr, k0 + q8), fragA(As, lr, 520 + k0 + q8),
                    ld8(WhhH + k0 + q8), ld8(WhhL + k0 + q8));
                mm3(a2, fragA(Ae, lr, k0 + q8), fragA(Ae, lr, 520 + k0 + q8),
                    ld8(WihH + k0 + q8), ld8(WihL + k0 + q8));
            }
#pragma unroll
            for (int r4 = 0; r4 < 4; r4++)
                zs[(quad * 4 + r4) * 132 + gate * 32 + nh * 16 + lr] =
                    a1[r4] + a2[r4] + biasA;
        }
        __syncthreads();
        {
            float zi = zs[ml * 132 + jj],      zf = zs[ml * 132 + 32 + jj];
            float zg = zs[ml * 132 + 64 + jj], zo = zs[ml * 132 + 96 + jj];
            c_reg = sigf(zf) * c_reg + sigf(zi) * tanhf(zg);
            float hv = sigf(zo) * tanhf(c_reg);
            ushort hb = f2bf(hv);
            ushort lb = f2bf(hv - bf2f(hb));
            __hip_atomic_store(&p.hP[(r0 + ml) * 512 + j0 + jj],
                               (uint)hb | ((uint)lb << 16), __ATOMIC_RELAXED, AGENT);
        }
        // ---- bar A (overlap: u1/u2 load + gumbel noise transcendentals) ----
        g++;
        int ipA = bar_arrive(bcl, p.cnt, p.gen, g);
        float U1 = __builtin_nontemporal_load(pu1 + t * 131072);
        float U2 = __builtin_nontemporal_load(pu2 + t * 131072);
        float noise = -logf(logf(U2 + EPS) / logf(U1 + EPS) + EPS);
        bar_wait(p.gen, g, ipA);

        // ==== Stage B: gate logits -> hf = h_t * hard_gate ===================
        stage_state(p.hP, r0, As);       // h_t (also stage A(t+1) operand)
        __syncthreads();
        {
            floatx4 acc = {};
#pragma unroll
            for (int k0 = 0; k0 < 128; k0 += 32)
                mm3(acc, fragA(As, lr, kq * 128 + k0 + q8),
                    fragA(As, lr, 520 + kq * 128 + k0 + q8),
                    ld8(WgH + k0 + q8), ld8(WgL + k0 + q8));
#pragma unroll
            for (int r4 = 0; r4 < 4; r4++)
                zs[kq * 528 + (quad * 4 + r4) * 33 + nh * 16 + lr] = acc[r4];
        }
        __syncthreads();
        {
            float z2 = zs[ml * 33 + jj] + zs[528 + ml * 33 + jj] +
                       zs[1056 + ml * 33 + jj] + zs[1584 + ml * 33 + jj];
            float logit = fmaxf(z2 + gy_r, 0.0f);
            bool gbit = sigf(logit + noise) >= 0.5f;
            ushort hb = As[ml * 1032 + j0 + jj];
            ushort lb = As[ml * 1032 + 520 + j0 + jj];
            uint pk = gbit ? ((uint)hb | ((uint)lb << 16)) : 0u;
            __hip_atomic_store(&p.hfP[(r0 + ml) * 512 + j0 + jj], pk,
                               __ATOMIC_RELAXED, AGENT);
        }
        // ---- bar B (overlap: stage Az = ht(t-1), 2 barriers old) -----------
        g++;
        int ipB = bar_arrive(bcl, p.cnt, p.gen, g);
        stage_state((t & 1) ? p.htP0 : p.htP1, r0, Az);
        bar_wait(p.gen, g, ipB);

        // ==== Stage C: z3 = hf@Wiht.T + ht@Whht.T -> ct, ht ==================
        stage_state(p.hfP, r0, Ac);
        __syncthreads();
        {
            floatx4 c1 = {}, c2 = {};
#pragma unroll
            for (int k0 = 0; k0 < 512; k0 += 32) {
                mm3(c1, fragA(Ac, lr, k0 + q8), fragA(Ac, lr, 520 + k0 + q8),
                    ld8(WitH + k0 + q8), ld8(WitL + k0 + q8));
                mm3(c2, fragA(Az, lr, k0 + q8), fragA(Az, lr, 520 + k0 + q8),
                    ld8(WhtH + k0 + q8), ld8(WhtL + k0 + q8));
            }
#pragma unroll
            for (int r4 = 0; r4 < 4; r4++)
                zs[(quad * 4 + r4) * 132 + gate * 32 + nh * 16 + lr] =
                    c1[r4] + c2[r4] + biasC;
        }
        __syncthreads();
        {
            float zi = zs[ml * 132 + jj],      zf = zs[ml * 132 + 32 + jj];
            float zg = zs[ml * 132 + 64 + jj], zo = zs[ml * 132 + 96 + jj];
            ct_reg = sigf(zf) * ct_reg + sigf(zi) * tanhf(zg);
            float hv = sigf(zo) * tanhf(ct_reg);
            ushort hb = f2bf(hv);
            ushort lb = f2bf(hv - bf2f(hb));
            int idx = (r0 + ml) * 512 + j0 + jj;
            uint* htcur = (t & 1) ? p.htP1 : p.htP0;
            __hip_atomic_store(&htcur[idx], (uint)hb | ((uint)lb << 16),
                               __ATOMIC_RELAXED, AGENT);
            if (t == 63) { p.ht_hi[idx] = hb; p.ht_lo[idx] = lb; }
        }
        // ---- bar C (overlap: stage emb rows for t+1) -----------------------
        g++;
        int ipC = bar_arrive(bcl, p.cnt, p.gen, g);
        if (t < 63) stage_emb(p.em_hi, p.em_lo, p.x, r0, t + 1, Ae);
        bar_wait(p.gen, g, ipC);
    }
}

// ---------------------------------------------------------------------------
// out = relu(ht @ Wlin.T + blin)  (M=256,N=256,K=512 hi/lo) -> fp32
// ---------------------------------------------------------------------------
__global__ __launch_bounds__(256) void k_final(const ushort* __restrict__ ht_hi,
                                               const ushort* __restrict__ ht_lo,
                                               const ushort* __restrict__ Wl_hi,
                                               const ushort* __restrict__ Wl_lo,
                                               const float* __restrict__ blin,
                                               float* __restrict__ out) {
    int tid = threadIdx.x, lane = tid & 63, w = tid >> 6;
    int wm = w & 1, wn = w >> 1, quad = lane >> 4, lr = lane & 15;
    int m0 = blockIdx.y * 64, n0 = blockIdx.x * 64;
    floatx4 acc[2][2] = {};
    for (int k0 = 0; k0 < 512; k0 += 32) {
        short8 ah[2], al[2], bh[2], bl[2];
#pragma unroll
        for (int tn = 0; tn < 2; tn++) {
            int n = n0 + wn * 32 + tn * 16 + lr;
            bh[tn] = ld8(Wl_hi + n * 512 + k0 + quad * 8);
            bl[tn] = ld8(Wl_lo + n * 512 + k0 + quad * 8);
        }
#pragma unroll
        for (int tm = 0; tm < 2; tm++) {
            int r = m0 + wm * 32 + tm * 16 + lr;
            ah[tm] = ld8(ht_hi + r * 512 + k0 + quad * 8);
            al[tm] = ld8(ht_lo + r * 512 + k0 + quad * 8);
        }
#pragma unroll
        for (int tm = 0; tm < 2; tm++)
#pragma unroll
            for (int tn = 0; tn < 2; tn++) mm3(acc[tm][tn], ah[tm], al[tm], bh[tn], bl[tn]);
    }
#pragma unroll
    for (int tm = 0; tm < 2; tm++)
#pragma unroll
        for (int tn = 0; tn < 2; tn++)
#pragma unroll
            for (int r4 = 0; r4 < 4; r4++) {
                int row = m0 + wm * 32 + tm * 16 + quad * 4 + r4;
                int n = n0 + wn * 32 + tn * 16 + lr;
                out[row * 256 + n] = fmaxf(acc[tm][tn][r4] + blin[n], 0.0f);
            }
}

// ---------------------------------------------------------------------------
extern "C" void kernel_launch(void* const* d_in, const int* in_sizes, int n_in,
                              void* d_out, int out_size, void* d_ws, size_t ws_size,
                              hipStream_t stream) {
    (void)in_sizes; (void)n_in; (void)out_size; (void)ws_size;
    const float* y      = (const float*)d_in[0];
    const int*   x      = (const int*)d_in[1];
    const float* emb    = (const float*)d_in[2];
    const float* W_ih   = (const float*)d_in[3];
    const float* W_hh   = (const float*)d_in[4];
    const float* b_ih   = (const float*)d_in[5];
    const float* b_hh   = (const float*)d_in[6];
    const float* W_iht  = (const float*)d_in[7];
    const float* W_hht  = (const float*)d_in[8];
    const float* b_iht  = (const float*)d_in[9];
    const float* b_hht  = (const float*)d_in[10];
    const float* Wg     = (const float*)d_in[11];
    const float* bg     = (const float*)d_in[12];
    const float* Wlin   = (const float*)d_in[13];
    const float* blin   = (const float*)d_in[14];
    const float* u1     = (const float*)d_in[15];
    const float* u2     = (const float*)d_in[16];
    float* out = (float*)d_out;

    // ws layout (uints): bar[4128] hP[131072] htP0[131072] htP1[131072]
    //                    hfP[131072] gy[131072 f32] ht_hi/ht_lo[131072 us] wreg
    uint* bar = (uint*)d_ws;            // cnt=bar[0], gen=bar[16], bcnt=bar+32 (stride 16)
    uint* hP   = bar + 4128;
    uint* htP0 = hP + 131072;
    uint* htP1 = htP0 + 131072;
    uint* hfP  = htP1 + 131072;
    float* gy  = (float*)(hfP + 131072);
    ushort* ht_hi = (ushort*)(gy + 131072);
    ushort* ht_lo = ht_hi + 131072;
    ushort* wreg  = ht_lo + 131072;

    KP p;
    p.b_ih = b_ih; p.b_hh = b_hh; p.b_iht = b_iht; p.b_hht = b_hht;
    p.u1 = u1; p.u2 = u2; p.gy = gy; p.x = x;
    p.cnt = &bar[0]; p.gen = &bar[16]; p.bcnt = bar + 32;
    p.hP = hP; p.htP0 = htP0; p.htP1 = htP1; p.hfP = hfP;
    p.ht_hi = ht_hi; p.ht_lo = ht_lo;
    p.Wih_hi  = wreg;             p.Wih_lo  = wreg + 1048576;
    p.Whh_hi  = wreg + 2097152;   p.Whh_lo  = wreg + 3145728;
    p.Wiht_hi = wreg + 4194304;   p.Wiht_lo = wreg + 5242880;
    p.Whht_hi = wreg + 6291456;   p.Whht_lo = wreg + 7340032;
    p.Wg_hi   = wreg + 8388608;   p.Wg_lo   = wreg + 9699328;
    p.em_hi   = wreg + 11272192;  p.em_lo   = wreg + 14450176;
    const ushort* Wl_hi = wreg + 11010048; const ushort* Wl_lo = wreg + 11141120;
    const ushort* y_hi  = wreg + 17628160; const ushort* y_lo  = wreg + 18152448;

    k_prep<<<dim3(38030), dim3(256), 0, stream>>>(W_ih, W_hh, W_iht, W_hht, Wg, Wlin,
                                                  emb, y, wreg, bar);
    k_gy<<<dim3(256), dim3(512), 0, stream>>>(y_hi, y_lo, p.Wg_hi, p.Wg_lo, bg, gy);

    void* args[] = {(void*)&p};
    hipLaunchCooperativeKernel((const void*)k_main, dim3(256), dim3(512), args, 0, stream);

    k_final<<<dim3(4, 4), dim3(256), 0, stream>>>(ht_hi, ht_lo, Wl_hi, Wl_lo, blin, out);
}

// Round 6
// 2894.812 us; speedup vs baseline: 3.5528x; 1.2090x over previous
//
#include <hip/hip_runtime.h>
#include <hip/hip_bf16.h>

// Doubly-recurrent LSTM + gumbel-sigmoid gate, B=256,T=64,H=512,V=6207,YF=2048.
// Persistent kernel. KEY: computation splits into 16 independent row-group
// pipelines (16 batch rows x 16 col-slice blocks each); barriers are per-group
// 16-block flag-line barriers (zero atomic contention, one IF round trip).
// Split-bf16 (hi+lo) MFMA, fp32 accumulate. State crosses blocks via
// AGENT-scope relaxed atomics; weights stay normally cached.

typedef __attribute__((ext_vector_type(8))) short short8;   // 8 bf16 = 1 MFMA operand
typedef __attribute__((ext_vector_type(4))) float floatx4;  // MFMA accumulator

#define MFMA16(a, b, c) __builtin_amdgcn_mfma_f32_16x16x32_bf16(a, b, c, 0, 0, 0)
#define AGENT __HIP_MEMORY_SCOPE_AGENT

__device__ inline float bf2f(ushort u) {
    union { unsigned int u32; float f; } v; v.u32 = ((unsigned int)u) << 16; return v.f;
}
__device__ inline ushort f2bf(float f) {  // RNE, finite inputs only
    union { float f; unsigned int u; } v; v.f = f;
    return (ushort)((v.u + 0x7fffu + ((v.u >> 16) & 1u)) >> 16);
}
__device__ inline short8 ld8(const ushort* p) { return *(const short8*)p; }
__device__ inline float sigf(float x) { return 1.0f / (1.0f + expf(-x)); }
__device__ inline void mm3(floatx4& acc, short8 ah, short8 al, short8 bh, short8 bl) {
    acc = MFMA16(ah, bh, acc);
    acc = MFMA16(ah, bl, acc);
    acc = MFMA16(al, bh, acc);
}

// ---------------------------------------------------------------------------
// prep: split fp32 arrays into bf16 hi/lo in wreg; zero flags + state.
// ---------------------------------------------------------------------------
__global__ __launch_bounds__(256) void k_prep(const float* __restrict__ w0,
                                              const float* __restrict__ w1,
                                              const float* __restrict__ w2,
                                              const float* __restrict__ w3,
                                              const float* __restrict__ wg,
                                              const float* __restrict__ wl,
                                              const float* __restrict__ em,
                                              const float* __restrict__ yy,
                                              ushort* __restrict__ wreg,
                                              uint* __restrict__ zbase) {
    unsigned i = blockIdx.x * 256u + threadIdx.x;
    if (i >= 9735712u) return;
    if (i >= 9338368u) {           // zero flags(4128) + hP + htP0 + htP1 (393216)
        zbase[i - 9338368u] = 0u;
        return;
    }
    const float* src; ushort* hi; unsigned n, loc;
    if (i < 4194304u) {
        unsigned seg = i >> 20; loc = i & 1048575u; n = 1048576u;
        hi = wreg + seg * 2097152u;
        src = (seg == 0) ? w0 : (seg == 1) ? w1 : (seg == 2) ? w2 : w3;
    } else if (i < 5505024u) { loc = i - 4194304u; src = wg; hi = wreg + 8388608u;  n = 1310720u; }
    else if (i < 5636096u)   { loc = i - 5505024u; src = wl; hi = wreg + 11010048u; n = 131072u; }
    else if (i < 8814080u)   { loc = i - 5636096u; src = em; hi = wreg + 11272192u; n = 3177984u; }
    else                     { loc = i - 8814080u; src = yy; hi = wreg + 17628160u; n = 524288u; }
    float v = src[loc];
    ushort h = f2bf(v);
    hi[loc] = h;
    hi[n + loc] = f2bf(v - bf2f(h));
}

// ---------------------------------------------------------------------------
// gy = y @ Wg[:,512:].T + bg  (M=256,N=512,K=2048; 256 blocks, 4-way K-split)
// ---------------------------------------------------------------------------
__global__ __launch_bounds__(512) void k_gy(const ushort* __restrict__ y_hi,
                                            const ushort* __restrict__ y_lo,
                                            const ushort* __restrict__ Wg_hi,
                                            const ushort* __restrict__ Wg_lo,
                                            const float* __restrict__ bg,
                                            float* __restrict__ gy) {
    __shared__ float zsB[4 * 528];
    int tid = threadIdx.x, lane = tid & 63, w = tid >> 6;
    int quad = lane >> 4, lr = lane & 15, q8 = quad * 8;
    int r0 = (blockIdx.x >> 4) * 16, n0 = (blockIdx.x & 15) * 32;
    int nh = w & 1, kq = w >> 1;
    int arow = r0 + lr, brow = n0 + nh * 16 + lr;
    floatx4 acc = {};
#pragma unroll
    for (int k0 = 0; k0 < 512; k0 += 32) {
        short8 ah = ld8(y_hi + arow * 2048 + kq * 512 + k0 + q8);
        short8 al = ld8(y_lo + arow * 2048 + kq * 512 + k0 + q8);
        short8 bh = ld8(Wg_hi + brow * 2560 + 512 + kq * 512 + k0 + q8);
        short8 bl = ld8(Wg_lo + brow * 2560 + 512 + kq * 512 + k0 + q8);
        mm3(acc, ah, al, bh, bl);
    }
#pragma unroll
    for (int r4 = 0; r4 < 4; r4++)
        zsB[kq * 528 + (quad * 4 + r4) * 33 + nh * 16 + lr] = acc[r4];
    __syncthreads();
    int ml = tid >> 5, jj = tid & 31;
    float s = zsB[ml * 33 + jj] + zsB[528 + ml * 33 + jj] +
              zsB[1056 + ml * 33 + jj] + zsB[1584 + ml * 33 + jj];
    gy[(r0 + ml) * 512 + n0 + jj] = s + bg[n0 + jj];
}

// ---------------------------------------------------------------------------
struct KP {
    const float *b_ih, *b_hh, *b_iht, *b_hht, *u1, *u2, *gy;
    const int* x;
    uint* gflags;                     // 16 groups x 16 flags (one 64B line each)
    uint *hP, *htP0, *htP1, *hfP;
    ushort *ht_hi, *ht_lo;
    const ushort *Whh_hi, *Whh_lo, *Wih_hi, *Wih_lo;
    const ushort *Wiht_hi, *Wiht_lo, *Whht_hi, *Whht_lo;
    const ushort *Wg_hi, *Wg_lo, *em_hi, *em_lo;
};

// Per-group 16-block flag-line barrier (no contended atomics).
// arrive: drain this block's stores, store generation into the group's line.
// wait: wave 0 polls the 16-flag line until all >= g.
__device__ inline void gbar_arrive(uint* gf, int jb, uint g) {
    __builtin_amdgcn_s_waitcnt(0);
    asm volatile("" ::: "memory");
    __syncthreads();                  // all 8 waves have drained their stores
    if (threadIdx.x == 0)
        __hip_atomic_store(&gf[jb], g, __ATOMIC_RELAXED, AGENT);
}
__device__ inline void gbar_wait(const uint* gf, uint g) {
    if ((threadIdx.x >> 6) == 0) {
        int l = threadIdx.x & 63;
        for (;;) {
            uint v = (l < 16) ? __hip_atomic_load(&gf[l], __ATOMIC_RELAXED, AGENT) : g;
            if (__all((int)(v >= g))) break;
            __builtin_amdgcn_s_sleep(1);
        }
    }
    __syncthreads();
}

// Stage 16 rows of a packed (hi|lo<<16) [256][512] buffer into LDS:
// hi at dst[r*1032 + c], lo at dst[r*1032 + 520 + c].
__device__ inline void stage_state(const uint* __restrict__ src, int r0,
                                   ushort* __restrict__ dst) {
    int tid = threadIdx.x;
    int sr = tid >> 5, scol = (tid & 31) * 16;
    const unsigned long long* p =
        (const unsigned long long*)(src + (r0 + sr) * 512 + scol);
    ushort* d = dst + sr * 1032;
#pragma unroll
    for (int i = 0; i < 8; i++) {
        unsigned long long v = __hip_atomic_load(p + i, __ATOMIC_RELAXED, AGENT);
        uint u0 = (uint)v, u1v = (uint)(v >> 32);
        int c = scol + i * 2;
        *(uint*)(d + c) = (u0 & 0xffffu) | ((u1v & 0xffffu) << 16);
        *(uint*)(d + 520 + c) = (u0 >> 16) | (u1v & 0xffff0000u);
    }
}

// Stage 16 emb rows (hi/lo planes, plain cached loads) into LDS, As layout.
__device__ inline void stage_emb(const ushort* __restrict__ emh,
                                 const ushort* __restrict__ eml,
                                 const int* __restrict__ x, int r0, int t,
                                 ushort* __restrict__ dst) {
    int tid = threadIdx.x;
    int sr = tid >> 5, sc = (tid & 31) * 16;
    int tok = x[(r0 + sr) * 64 + t];
    const short8* ph = (const short8*)(emh + (size_t)tok * 512 + sc);
    const short8* pl = (const short8*)(eml + (size_t)tok * 512 + sc);
    short8 h0 = ph[0], h1 = ph[1], l0 = pl[0], l1 = pl[1];
    ushort* d = dst + sr * 1032;
    *(short8*)(d + sc) = h0;       *(short8*)(d + sc + 8) = h1;
    *(short8*)(d + 520 + sc) = l0; *(short8*)(d + 520 + sc + 8) = l1;
}

__device__ inline short8 fragA(const ushort* As, int row, int k) {
    return *(const short8*)(As + row * 1032 + k);
}

__global__ void __launch_bounds__(512, 1) k_main(KP p) {
    __shared__ ushort As[16 * 1032];   // h tile (stage B stages h_t; stage A(t+1) reuses)
    __shared__ ushort Ae[16 * 1032];   // emb rows for current t (staged during bar-C wait)
    __shared__ ushort Az[16 * 1032];   // ht(t-1) tile (staged during bar-B wait)
    __shared__ ushort Ac[16 * 1032];   // hf tile
    __shared__ float zs[16 * 132];     // stage A/C epilogue; B K-split partials

    const int bid = blockIdx.x;            // 0..255
    const int tid = threadIdx.x;           // 0..511
    const int w = tid >> 6;                // wave 0..7
    const int lane = tid & 63;
    const int quad = lane >> 4;
    const int lr = lane & 15;
    const int q8 = quad * 8;
    const float EPS = 1e-10f;

    const int g16 = bid >> 4, jb = bid & 15;
    const int r0 = g16 * 16, j0 = jb * 32;
    const int gate = w >> 1, nh = w & 1;
    const int brow = gate * 512 + j0 + nh * 16 + lr;   // stage A/C weight row
    const int kq = w >> 1;                              // stage B K-split window
    const int browB = j0 + nh * 16 + lr;                // stage B Wg row
    const int ml = tid >> 5, jj = tid & 31;             // epilogue element

    // hoisted loop-invariants
    const float biasA = p.b_ih[brow] + p.b_hh[brow];
    const float biasC = p.b_iht[brow] + p.b_hht[brow];
    const float gy_r = p.gy[(r0 + ml) * 512 + j0 + jj];
    const ushort* WhhH = p.Whh_hi + brow * 512;
    const ushort* WhhL = p.Whh_lo + brow * 512;
    const ushort* WihH = p.Wih_hi + brow * 512;
    const ushort* WihL = p.Wih_lo + brow * 512;
    const ushort* WitH = p.Wiht_hi + brow * 512;
    const ushort* WitL = p.Wiht_lo + brow * 512;
    const ushort* WhtH = p.Whht_hi + brow * 512;
    const ushort* WhtL = p.Whht_lo + brow * 512;
    const ushort* WgH = p.Wg_hi + browB * 2560 + kq * 128;
    const ushort* WgL = p.Wg_lo + browB * 2560 + kq * 128;
    const float* pu1 = p.u1 + (r0 + ml) * 512 + j0 + jj;
    const float* pu2 = p.u2 + (r0 + ml) * 512 + j0 + jj;
    uint* gf = p.gflags + g16 * 16;    // this group's 64B flag line

    // init: h(-1) = 0 in As; emb rows for t=0 into Ae
    for (int i = tid; i < 16 * 1032; i += 512) As[i] = 0;
    stage_emb(p.em_hi, p.em_lo, p.x, r0, 0, Ae);
    __syncthreads();

    float c_reg = 0.0f, ct_reg = 0.0f;
    uint g = 0;

    for (int t = 0; t < 64; t++) {
        // ==== Stage A: z1 = h@Whh.T + emb@Wih.T -> c, h ======================
        {
            floatx4 a1 = {}, a2 = {};
#pragma unroll
            for (int k0 = 0; k0 < 512; k0 += 32) {
                mm3(a1, fragA(As, lr, k0 + q8), fragA(As, lr, 520 + k0 + q8),
                    ld8(WhhH + k0 + q8), ld8(WhhL + k0 + q8));
                mm3(a2, fragA(Ae, lr, k0 + q8), fragA(Ae, lr, 520 + k0 + q8),
                    ld8(WihH + k0 + q8), ld8(WihL + k0 + q8));
            }
#pragma unroll
            for (int r4 = 0; r4 < 4; r4++)
                zs[(quad * 4 + r4) * 132 + gate * 32 + nh * 16 + lr] =
                    a1[r4] + a2[r4] + biasA;
        }
        __syncthreads();
        {
            float zi = zs[ml * 132 + jj],      zf = zs[ml * 132 + 32 + jj];
            float zg = zs[ml * 132 + 64 + jj], zo = zs[ml * 132 + 96 + jj];
            c_reg = sigf(zf) * c_reg + sigf(zi) * tanhf(zg);
            float hv = sigf(zo) * tanhf(c_reg);
            ushort hb = f2bf(hv);
            ushort lb = f2bf(hv - bf2f(hb));
            __hip_atomic_store(&p.hP[(r0 + ml) * 512 + j0 + jj],
                               (uint)hb | ((uint)lb << 16), __ATOMIC_RELAXED, AGENT);
        }
        // ---- bar A (overlap: u1/u2 load + gumbel noise transcendentals) ----
        g++;
        gbar_arrive(gf, jb, g);
        float U1 = __builtin_nontemporal_load(pu1 + t * 131072);
        float U2 = __builtin_nontemporal_load(pu2 + t * 131072);
        float noise = -logf(logf(U2 + EPS) / logf(U1 + EPS) + EPS);
        gbar_wait(gf, g);

        // ==== Stage B: gate logits -> hf = h_t * hard_gate ===================
        stage_state(p.hP, r0, As);       // h_t (also stage A(t+1) operand)
        __syncthreads();
        {
            floatx4 acc = {};
#pragma unroll
            for (int k0 = 0; k0 < 128; k0 += 32)
                mm3(acc, fragA(As, lr, kq * 128 + k0 + q8),
                    fragA(As, lr, 520 + kq * 128 + k0 + q8),
                    ld8(WgH + k0 + q8), ld8(WgL + k0 + q8));
#pragma unroll
            for (int r4 = 0; r4 < 4; r4++)
                zs[kq * 528 + (quad * 4 + r4) * 33 + nh * 16 + lr] = acc[r4];
        }
        __syncthreads();
        {
            float z2 = zs[ml * 33 + jj] + zs[528 + ml * 33 + jj] +
                       zs[1056 + ml * 33 + jj] + zs[1584 + ml * 33 + jj];
            float logit = fmaxf(z2 + gy_r, 0.0f);
            bool gbit = sigf(logit + noise) >= 0.5f;
            ushort hb = As[ml * 1032 + j0 + jj];
            ushort lb = As[ml * 1032 + 520 + j0 + jj];
            uint pk = gbit ? ((uint)hb | ((uint)lb << 16)) : 0u;
            __hip_atomic_store(&p.hfP[(r0 + ml) * 512 + j0 + jj], pk,
                               __ATOMIC_RELAXED, AGENT);
        }
        // ---- bar B (overlap: stage Az = ht(t-1), 2 barriers old) -----------
        g++;
        gbar_arrive(gf, jb, g);
        stage_state((t & 1) ? p.htP0 : p.htP1, r0, Az);
        gbar_wait(gf, g);

        // ==== Stage C: z3 = hf@Wiht.T + ht@Whht.T -> ct, ht ==================
        stage_state(p.hfP, r0, Ac);
        __syncthreads();
        {
            floatx4 c1 = {}, c2 = {};
#pragma unroll
            for (int k0 = 0; k0 < 512; k0 += 32) {
                mm3(c1, fragA(Ac, lr, k0 + q8), fragA(Ac, lr, 520 + k0 + q8),
                    ld8(WitH + k0 + q8), ld8(WitL + k0 + q8));
                mm3(c2, fragA(Az, lr, k0 + q8), fragA(Az, lr, 520 + k0 + q8),
                    ld8(WhtH + k0 + q8), ld8(WhtL + k0 + q8));
            }
#pragma unroll
            for (int r4 = 0; r4 < 4; r4++)
                zs[(quad * 4 + r4) * 132 + gate * 32 + nh * 16 + lr] =
                    c1[r4] + c2[r4] + biasC;
        }
        __syncthreads();
        {
            float zi = zs[ml * 132 + jj],      zf = zs[ml * 132 + 32 + jj];
            float zg = zs[ml * 132 + 64 + jj], zo = zs[ml * 132 + 96 + jj];
            ct_reg = sigf(zf) * ct_reg + sigf(zi) * tanhf(zg);
            float hv = sigf(zo) * tanhf(ct_reg);
            ushort hb = f2bf(hv);
            ushort lb = f2bf(hv - bf2f(hb));
            int idx = (r0 + ml) * 512 + j0 + jj;
            uint* htcur = (t & 1) ? p.htP1 : p.htP0;
            __hip_atomic_store(&htcur[idx], (uint)hb | ((uint)lb << 16),
                               __ATOMIC_RELAXED, AGENT);
            if (t == 63) { p.ht_hi[idx] = hb; p.ht_lo[idx] = lb; }
        }
        // ---- bar C (overlap: stage emb rows for t+1) -----------------------
        g++;
        gbar_arrive(gf, jb, g);
        if (t < 63) stage_emb(p.em_hi, p.em_lo, p.x, r0, t + 1, Ae);
        gbar_wait(gf, g);
    }
}

// ---------------------------------------------------------------------------
// out = relu(ht @ Wlin.T + blin)  (M=256,N=256,K=512 hi/lo) -> fp32
// ---------------------------------------------------------------------------
__global__ __launch_bounds__(256) void k_final(const ushort* __restrict__ ht_hi,
                                               const ushort* __restrict__ ht_lo,
                                               const ushort* __restrict__ Wl_hi,
                                               const ushort* __restrict__ Wl_lo,
                                               const float* __restrict__ blin,
                                               float* __restrict__ out) {
    int tid = threadIdx.x, lane = tid & 63, w = tid >> 6;
    int wm = w & 1, wn = w >> 1, quad = lane >> 4, lr = lane & 15;
    int m0 = blockIdx.y * 64, n0 = blockIdx.x * 64;
    floatx4 acc[2][2] = {};
    for (int k0 = 0; k0 < 512; k0 += 32) {
        short8 ah[2], al[2], bh[2], bl[2];
#pragma unroll
        for (int tn = 0; tn < 2; tn++) {
            int n = n0 + wn * 32 + tn * 16 + lr;
            bh[tn] = ld8(Wl_hi + n * 512 + k0 + quad * 8);
            bl[tn] = ld8(Wl_lo + n * 512 + k0 + quad * 8);
        }
#pragma unroll
        for (int tm = 0; tm < 2; tm++) {
            int r = m0 + wm * 32 + tm * 16 + lr;
            ah[tm] = ld8(ht_hi + r * 512 + k0 + quad * 8);
            al[tm] = ld8(ht_lo + r * 512 + k0 + quad * 8);
        }
#pragma unroll
        for (int tm = 0; tm < 2; tm++)
#pragma unroll
            for (int tn = 0; tn < 2; tn++) mm3(acc[tm][tn], ah[tm], al[tm], bh[tn], bl[tn]);
    }
#pragma unroll
    for (int tm = 0; tm < 2; tm++)
#pragma unroll
        for (int tn = 0; tn < 2; tn++)
#pragma unroll
            for (int r4 = 0; r4 < 4; r4++) {
                int row = m0 + wm * 32 + tm * 16 + quad * 4 + r4;
                int n = n0 + wn * 32 + tn * 16 + lr;
                out[row * 256 + n] = fmaxf(acc[tm][tn][r4] + blin[n], 0.0f);
            }
}

// ---------------------------------------------------------------------------
extern "C" void kernel_launch(void* const* d_in, const int* in_sizes, int n_in,
                              void* d_out, int out_size, void* d_ws, size_t ws_size,
                              hipStream_t stream) {
    (void)in_sizes; (void)n_in; (void)out_size; (void)ws_size;
    const float* y      = (const float*)d_in[0];
    const int*   x      = (const int*)d_in[1];
    const float* emb    = (const float*)d_in[2];
    const float* W_ih   = (const float*)d_in[3];
    const float* W_hh   = (const float*)d_in[4];
    const float* b_ih   = (const float*)d_in[5];
    const float* b_hh   = (const float*)d_in[6];
    const float* W_iht  = (const float*)d_in[7];
    const float* W_hht  = (const float*)d_in[8];
    const float* b_iht  = (const float*)d_in[9];
    const float* b_hht  = (const float*)d_in[10];
    const float* Wg     = (const float*)d_in[11];
    const float* bg     = (const float*)d_in[12];
    const float* Wlin   = (const float*)d_in[13];
    const float* blin   = (const float*)d_in[14];
    const float* u1     = (const float*)d_in[15];
    const float* u2     = (const float*)d_in[16];
    float* out = (float*)d_out;

    // ws layout (uints): flags[4128] hP[131072] htP0[131072] htP1[131072]
    //                    hfP[131072] gy[131072 f32] ht_hi/ht_lo[131072 us] wreg
    uint* bar = (uint*)d_ws;            // gflags = bar (16 groups x 16 uints)
    uint* hP   = bar + 4128;
    uint* htP0 = hP + 131072;
    uint* htP1 = htP0 + 131072;
    uint* hfP  = htP1 + 131072;
    float* gy  = (float*)(hfP + 131072);
    ushort* ht_hi = (ushort*)(gy + 131072);
    ushort* ht_lo = ht_hi + 131072;
    ushort* wreg  = ht_lo + 131072;

    KP p;
    p.b_ih = b_ih; p.b_hh = b_hh; p.b_iht = b_iht; p.b_hht = b_hht;
    p.u1 = u1; p.u2 = u2; p.gy = gy; p.x = x;
    p.gflags = bar;
    p.hP = hP; p.htP0 = htP0; p.htP1 = htP1; p.hfP = hfP;
    p.ht_hi = ht_hi; p.ht_lo = ht_lo;
    p.Wih_hi  = wreg;             p.Wih_lo  = wreg + 1048576;
    p.Whh_hi  = wreg + 2097152;   p.Whh_lo  = wreg + 3145728;
    p.Wiht_hi = wreg + 4194304;   p.Wiht_lo = wreg + 5242880;
    p.Whht_hi = wreg + 6291456;   p.Whht_lo = wreg + 7340032;
    p.Wg_hi   = wreg + 8388608;   p.Wg_lo   = wreg + 9699328;
    p.em_hi   = wreg + 11272192;  p.em_lo   = wreg + 14450176;
    const ushort* Wl_hi = wreg + 11010048; const ushort* Wl_lo = wreg + 11141120;
    const ushort* y_hi  = wreg + 17628160; const ushort* y_lo  = wreg + 18152448;

    k_prep<<<dim3(38030), dim3(256), 0, stream>>>(W_ih, W_hh, W_iht, W_hht, Wg, Wlin,
                                                  emb, y, wreg, bar);
    k_gy<<<dim3(256), dim3(512), 0, stream>>>(y_hi, y_lo, p.Wg_hi, p.Wg_lo, bg, gy);

    void* args[] = {(void*)&p};
    hipLaunchCooperativeKernel((const void*)k_main, dim3(256), dim3(512), args, 0, stream);

    k_final<<<dim3(4, 4), dim3(256), 0, stream>>>(ht_hi, ht_lo, Wl_hi, Wl_lo, blin, out);
}

// Round 7
// 2825.604 us; speedup vs baseline: 3.6399x; 1.0245x over previous
//
#include <hip/hip_runtime.h>
#include <hip/hip_bf16.h>

// Doubly-recurrent LSTM + gumbel-sigmoid gate, B=256,T=64,H=512,V=6207,YF=2048.
// Persistent kernel; 16 independent row-group pipelines with per-group 16-block
// flag-line barriers (2 per step). XCD-aware dynamic role assignment pins each
// jb weight slice to one XCD so weights stay L2-resident (per-XCD footprint
// ~2.2 MB < 4 MB L2). Split-bf16 (hi+lo) MFMA, fp32 accumulate. State crosses
// blocks via AGENT-scope relaxed atomics (IF-coherent).

typedef __attribute__((ext_vector_type(8))) short short8;   // 8 bf16 = 1 MFMA operand
typedef __attribute__((ext_vector_type(4))) float floatx4;  // MFMA accumulator

#define MFMA16(a, b, c) __builtin_amdgcn_mfma_f32_16x16x32_bf16(a, b, c, 0, 0, 0)
#define AGENT __HIP_MEMORY_SCOPE_AGENT
// s_getreg HWREG(XCC_ID=20, offset=0, size=32)  [measured: learn_hip m09]
#define HWREG_XCC_ID ((31u << 11) | (0u << 6) | 20u)

__device__ inline float bf2f(ushort u) {
    union { unsigned int u32; float f; } v; v.u32 = ((unsigned int)u) << 16; return v.f;
}
__device__ inline ushort f2bf(float f) {  // RNE, finite inputs only
    union { float f; unsigned int u; } v; v.f = f;
    return (ushort)((v.u + 0x7fffu + ((v.u >> 16) & 1u)) >> 16);
}
__device__ inline short8 ld8(const ushort* p) { return *(const short8*)p; }
__device__ inline float sigf(float x) { return 1.0f / (1.0f + expf(-x)); }
__device__ inline void mm3(floatx4& acc, short8 ah, short8 al, short8 bh, short8 bl) {
    acc = MFMA16(ah, bh, acc);
    acc = MFMA16(ah, bl, acc);
    acc = MFMA16(al, bh, acc);
}

// ---------------------------------------------------------------------------
// prep: split fp32 arrays into bf16 hi/lo in wreg; zero flags/claim + state.
// ---------------------------------------------------------------------------
__global__ __launch_bounds__(256) void k_prep(const float* __restrict__ w0,
                                              const float* __restrict__ w1,
                                              const float* __restrict__ w2,
                                              const float* __restrict__ w3,
                                              const float* __restrict__ wg,
                                              const float* __restrict__ wl,
                                              const float* __restrict__ em,
                                              const float* __restrict__ yy,
                                              ushort* __restrict__ wreg,
                                              uint* __restrict__ zbase) {
    unsigned i = blockIdx.x * 256u + threadIdx.x;
    if (i >= 9735712u) return;
    if (i >= 9338368u) {           // zero flags+claim(4128) + hP + htP0 + htP1
        zbase[i - 9338368u] = 0u;
        return;
    }
    const float* src; ushort* hi; unsigned n, loc;
    if (i < 4194304u) {
        unsigned seg = i >> 20; loc = i & 1048575u; n = 1048576u;
        hi = wreg + seg * 2097152u;
        src = (seg == 0) ? w0 : (seg == 1) ? w1 : (seg == 2) ? w2 : w3;
    } else if (i < 5505024u) { loc = i - 4194304u; src = wg; hi = wreg + 8388608u;  n = 1310720u; }
    else if (i < 5636096u)   { loc = i - 5505024u; src = wl; hi = wreg + 11010048u; n = 131072u; }
    else if (i < 8814080u)   { loc = i - 5636096u; src = em; hi = wreg + 11272192u; n = 3177984u; }
    else                     { loc = i - 8814080u; src = yy; hi = wreg + 17628160u; n = 524288u; }
    float v = src[loc];
    ushort h = f2bf(v);
    hi[loc] = h;
    hi[n + loc] = f2bf(v - bf2f(h));
}

// ---------------------------------------------------------------------------
// gy = y @ Wg[:,512:].T + bg  (M=256,N=512,K=2048; 256 blocks, 4-way K-split)
// ---------------------------------------------------------------------------
__global__ __launch_bounds__(512) void k_gy(const ushort* __restrict__ y_hi,
                                            const ushort* __restrict__ y_lo,
                                            const ushort* __restrict__ Wg_hi,
                                            const ushort* __restrict__ Wg_lo,
                                            const float* __restrict__ bg,
                                            float* __restrict__ gy) {
    __shared__ float zsB[4 * 528];
    int tid = threadIdx.x, lane = tid & 63, w = tid >> 6;
    int quad = lane >> 4, lr = lane & 15, q8 = quad * 8;
    int r0 = (blockIdx.x >> 4) * 16, n0 = (blockIdx.x & 15) * 32;
    int nh = w & 1, kq = w >> 1;
    int arow = r0 + lr, brow = n0 + nh * 16 + lr;
    floatx4 acc = {};
#pragma unroll
    for (int k0 = 0; k0 < 512; k0 += 32) {
        short8 ah = ld8(y_hi + arow * 2048 + kq * 512 + k0 + q8);
        short8 al = ld8(y_lo + arow * 2048 + kq * 512 + k0 + q8);
        short8 bh = ld8(Wg_hi + brow * 2560 + 512 + kq * 512 + k0 + q8);
        short8 bl = ld8(Wg_lo + brow * 2560 + 512 + kq * 512 + k0 + q8);
        mm3(acc, ah, al, bh, bl);
    }
#pragma unroll
    for (int r4 = 0; r4 < 4; r4++)
        zsB[kq * 528 + (quad * 4 + r4) * 33 + nh * 16 + lr] = acc[r4];
    __syncthreads();
    int ml = tid >> 5, jj = tid & 31;
    float s = zsB[ml * 33 + jj] + zsB[528 + ml * 33 + jj] +
              zsB[1056 + ml * 33 + jj] + zsB[1584 + ml * 33 + jj];
    gy[(r0 + ml) * 512 + n0 + jj] = s + bg[n0 + jj];
}

// ---------------------------------------------------------------------------
struct KP {
    const float *b_ih, *b_hh, *b_iht, *b_hht, *u1, *u2, *gy;
    const int* x;
    uint* gflags;                     // 16 groups x 16 flags (one 64B line each)
    uint* claim;                      // 8 XCDs x 16-uint stride claim counters
    uint *hP, *htP0, *htP1, *hfP;
    ushort *ht_hi, *ht_lo;
    const ushort *Whh_hi, *Whh_lo, *Wih_hi, *Wih_lo;
    const ushort *Wiht_hi, *Wiht_lo, *Whht_hi, *Whht_lo;
    const ushort *Wg_hi, *Wg_lo, *em_hi, *em_lo;
};

// Per-group 16-block flag-line barrier (no contended atomics).
__device__ inline void gbar_arrive(uint* gf, int jb, uint g) {
    __builtin_amdgcn_s_waitcnt(0);
    asm volatile("" ::: "memory");
    __syncthreads();                  // all 8 waves have drained their stores
    if (threadIdx.x == 0)
        __hip_atomic_store(&gf[jb], g, __ATOMIC_RELAXED, AGENT);
}
__device__ inline void gbar_wait(const uint* gf, uint g) {
    if ((threadIdx.x >> 6) == 0) {
        int l = threadIdx.x & 63;
        for (;;) {
            uint v = (l < 16) ? __hip_atomic_load(&gf[l], __ATOMIC_RELAXED, AGENT) : g;
            if (__all((int)(v >= g))) break;
            __builtin_amdgcn_s_sleep(1);
        }
    }
    __syncthreads();
}

// Stage 16 rows of a packed (hi|lo<<16) [256][512] buffer into LDS:
// hi at dst[r*1032 + c], lo at dst[r*1032 + 520 + c].
__device__ inline void stage_state(const uint* __restrict__ src, int r0,
                                   ushort* __restrict__ dst) {
    int tid = threadIdx.x;
    int sr = tid >> 5, scol = (tid & 31) * 16;
    const unsigned long long* p =
        (const unsigned long long*)(src + (r0 + sr) * 512 + scol);
    ushort* d = dst + sr * 1032;
#pragma unroll
    for (int i = 0; i < 8; i++) {
        unsigned long long v = __hip_atomic_load(p + i, __ATOMIC_RELAXED, AGENT);
        uint u0 = (uint)v, u1v = (uint)(v >> 32);
        int c = scol + i * 2;
        *(uint*)(d + c) = (u0 & 0xffffu) | ((u1v & 0xffffu) << 16);
        *(uint*)(d + 520 + c) = (u0 >> 16) | (u1v & 0xffff0000u);
    }
}

// Stage 16 emb rows (hi/lo planes, plain cached loads) into LDS, As layout.
__device__ inline void stage_emb(const ushort* __restrict__ emh,
                                 const ushort* __restrict__ eml,
                                 const int* __restrict__ x, int r0, int t,
                                 ushort* __restrict__ dst) {
    int tid = threadIdx.x;
    int sr = tid >> 5, sc = (tid & 31) * 16;
    int tok = x[(r0 + sr) * 64 + t];
    const short8* ph = (const short8*)(emh + (size_t)tok * 512 + sc);
    const short8* pl = (const short8*)(eml + (size_t)tok * 512 + sc);
    short8 h0 = ph[0], h1 = ph[1], l0 = pl[0], l1 = pl[1];
    ushort* d = dst + sr * 1032;
    *(short8*)(d + sc) = h0;       *(short8*)(d + sc + 8) = h1;
    *(short8*)(d + 520 + sc) = l0; *(short8*)(d + 520 + sc + 8) = l1;
}

__device__ inline short8 fragA(const ushort* As, int row, int k) {
    return *(const short8*)(As + row * 1032 + k);
}

__global__ void __launch_bounds__(512, 1) k_main(KP p) {
    __shared__ ushort As[16 * 1032];   // h tile (stage B stages h_t; stage A(t+1) reuses)
    __shared__ ushort Ae[16 * 1032];   // emb rows for current t (staged in barB window)
    __shared__ ushort Az[16 * 1032];   // ht(t-1) tile (staged in barB window)
    __shared__ ushort Ac[16 * 1032];   // hf tile
    __shared__ float zs[16 * 132];     // stage A/C epilogue; B K-split partials
    __shared__ uint role_s;

    const int tid = threadIdx.x;           // 0..511
    const int w = tid >> 6;                // wave 0..7
    const int lane = tid & 63;
    const int quad = lane >> 4;
    const int lr = lane & 15;
    const int q8 = quad * 8;
    const float EPS = 1e-10f;

    // ---- XCD-aware role claim: jb pinned to XCD so weight slices are
    // L2-resident no matter the hardware block->XCD mapping. LDS forces
    // 1 block/CU => exactly 32 blocks/XCD. Degenerate (uniform XCC read)
    // still yields a valid role permutation.
    if (tid == 0) {
        uint xcc = __builtin_amdgcn_s_getreg(HWREG_XCC_ID) & 7u;
        uint slot = __hip_atomic_fetch_add(&p.claim[xcc * 16], 1u,
                                           __ATOMIC_RELAXED, AGENT) & 31u;
        role_s = xcc * 32u + slot;
    }
    __syncthreads();
    const uint role = role_s;
    const int jb = (int)(role >> 4);       // xcc*2 + (slot>>4)
    const int g16 = (int)(role & 15u);
    const int r0 = g16 * 16, j0 = jb * 32;

    const int gate = w >> 1, nh = w & 1;
    const int brow = gate * 512 + j0 + nh * 16 + lr;   // stage A/C weight row
    const int kq = w >> 1;                              // stage B K-split window
    const int browB = j0 + nh * 16 + lr;                // stage B Wg row
    const int ml = tid >> 5, jj = tid & 31;             // epilogue element

    // hoisted loop-invariants
    const float biasA = p.b_ih[brow] + p.b_hh[brow];
    const float biasC = p.b_iht[brow] + p.b_hht[brow];
    const float gy_r = p.gy[(r0 + ml) * 512 + j0 + jj];
    const ushort* WhhH = p.Whh_hi + brow * 512;
    const ushort* WhhL = p.Whh_lo + brow * 512;
    const ushort* WihH = p.Wih_hi + brow * 512;
    const ushort* WihL = p.Wih_lo + brow * 512;
    const ushort* WitH = p.Wiht_hi + brow * 512;
    const ushort* WitL = p.Wiht_lo + brow * 512;
    const ushort* WhtH = p.Whht_hi + brow * 512;
    const ushort* WhtL = p.Whht_lo + brow * 512;
    const ushort* WgH = p.Wg_hi + browB * 2560 + kq * 128;
    const ushort* WgL = p.Wg_lo + browB * 2560 + kq * 128;
    const float* pu1 = p.u1 + (r0 + ml) * 512 + j0 + jj;
    const float* pu2 = p.u2 + (r0 + ml) * 512 + j0 + jj;
    uint* gf = p.gflags + g16 * 16;    // this group's 64B flag line

    // init: h(-1) = 0 in As; emb rows for t=0 into Ae
    for (int i = tid; i < 16 * 1032; i += 512) As[i] = 0;
    stage_emb(p.em_hi, p.em_lo, p.x, r0, 0, Ae);
    __syncthreads();

    float c_reg = 0.0f, ct_reg = 0.0f;
    uint g = 0;

    for (int t = 0; t < 64; t++) {
        // ==== Stage A: z1 = h@Whh.T + emb@Wih.T -> c, h ======================
        {
            floatx4 a1 = {}, a2 = {};
#pragma unroll
            for (int k0 = 0; k0 < 512; k0 += 32) {
                mm3(a1, fragA(As, lr, k0 + q8), fragA(As, lr, 520 + k0 + q8),
                    ld8(WhhH + k0 + q8), ld8(WhhL + k0 + q8));
                mm3(a2, fragA(Ae, lr, k0 + q8), fragA(Ae, lr, 520 + k0 + q8),
                    ld8(WihH + k0 + q8), ld8(WihL + k0 + q8));
            }
#pragma unroll
            for (int r4 = 0; r4 < 4; r4++)
                zs[(quad * 4 + r4) * 132 + gate * 32 + nh * 16 + lr] =
                    a1[r4] + a2[r4] + biasA;
        }
        __syncthreads();
        {
            float zi = zs[ml * 132 + jj],      zf = zs[ml * 132 + 32 + jj];
            float zg = zs[ml * 132 + 64 + jj], zo = zs[ml * 132 + 96 + jj];
            c_reg = sigf(zf) * c_reg + sigf(zi) * tanhf(zg);
            float hv = sigf(zo) * tanhf(c_reg);
            ushort hb = f2bf(hv);
            ushort lb = f2bf(hv - bf2f(hb));
            __hip_atomic_store(&p.hP[(r0 + ml) * 512 + j0 + jj],
                               (uint)hb | ((uint)lb << 16), __ATOMIC_RELAXED, AGENT);
        }
        // ---- bar A (overlap: u1/u2 load + gumbel noise transcendentals) ----
        g++;
        gbar_arrive(gf, jb, g);
        float U1 = __builtin_nontemporal_load(pu1 + t * 131072);
        float U2 = __builtin_nontemporal_load(pu2 + t * 131072);
        float noise = -logf(logf(U2 + EPS) / logf(U1 + EPS) + EPS);
        gbar_wait(gf, g);

        // ==== Stage B: gate logits -> hf = h_t * hard_gate ===================
        stage_state(p.hP, r0, As);       // h_t (also stage A(t+1) operand)
        __syncthreads();
        {
            floatx4 acc = {};
#pragma unroll
            for (int k0 = 0; k0 < 128; k0 += 32)
                mm3(acc, fragA(As, lr, kq * 128 + k0 + q8),
                    fragA(As, lr, 520 + kq * 128 + k0 + q8),
                    ld8(WgH + k0 + q8), ld8(WgL + k0 + q8));
#pragma unroll
            for (int r4 = 0; r4 < 4; r4++)
                zs[kq * 528 + (quad * 4 + r4) * 33 + nh * 16 + lr] = acc[r4];
        }
        __syncthreads();
        {
            float z2 = zs[ml * 33 + jj] + zs[528 + ml * 33 + jj] +
                       zs[1056 + ml * 33 + jj] + zs[1584 + ml * 33 + jj];
            float logit = fmaxf(z2 + gy_r, 0.0f);
            bool gbit = sigf(logit + noise) >= 0.5f;
            ushort hb = As[ml * 1032 + j0 + jj];
            ushort lb = As[ml * 1032 + 520 + j0 + jj];
            uint pk = gbit ? ((uint)hb | ((uint)lb << 16)) : 0u;
            __hip_atomic_store(&p.hfP[(r0 + ml) * 512 + j0 + jj], pk,
                               __ATOMIC_RELAXED, AGENT);
        }
        // ---- bar B (overlap: stage Az = ht(t-1) + emb rows for t+1) --------
        // Safe: all C(t-1) stores were drained at barA(t) arrival, so htP is
        // consistent; Ae is idle after stage A.
        g++;
        gbar_arrive(gf, jb, g);
        stage_state((t & 1) ? p.htP0 : p.htP1, r0, Az);
        if (t < 63) stage_emb(p.em_hi, p.em_lo, p.x, r0, t + 1, Ae);
        gbar_wait(gf, g);

        // ==== Stage C: z3 = hf@Wiht.T + ht@Whht.T -> ct, ht ==================
        // No barrier after C: stage A(t+1) depends only on As (already local)
        // and Ae; hP isn't rewritten until A(t+1) which is ordered after
        // barB(t) (all stage-B readers of hP have finished); htP readers (Az
        // staging) are ordered after barA of the following step.
        stage_state(p.hfP, r0, Ac);
        __syncthreads();
        {
            floatx4 c1 = {}, c2 = {};
#pragma unroll
            for (int k0 = 0; k0 < 512; k0 += 32) {
                mm3(c1, fragA(Ac, lr, k0 + q8), fragA(Ac, lr, 520 + k0 + q8),
                    ld8(WitH + k0 + q8), ld8(WitL + k0 + q8));
                mm3(c2, fragA(Az, lr, k0 + q8), fragA(Az, lr, 520 + k0 + q8),
                    ld8(WhtH + k0 + q8), ld8(WhtL + k0 + q8));
            }
#pragma unroll
            for (int r4 = 0; r4 < 4; r4++)
                zs[(quad * 4 + r4) * 132 + gate * 32 + nh * 16 + lr] =
                    c1[r4] + c2[r4] + biasC;
        }
        __syncthreads();
        {
            float zi = zs[ml * 132 + jj],      zf = zs[ml * 132 + 32 + jj];
            float zg = zs[ml * 132 + 64 + jj], zo = zs[ml * 132 + 96 + jj];
            ct_reg = sigf(zf) * ct_reg + sigf(zi) * tanhf(zg);
            float hv = sigf(zo) * tanhf(ct_reg);
            ushort hb = f2bf(hv);
            ushort lb = f2bf(hv - bf2f(hb));
            int idx = (r0 + ml) * 512 + j0 + jj;
            uint* htcur = (t & 1) ? p.htP1 : p.htP0;
            __hip_atomic_store(&htcur[idx], (uint)hb | ((uint)lb << 16),
                               __ATOMIC_RELAXED, AGENT);
            if (t == 63) { p.ht_hi[idx] = hb; p.ht_lo[idx] = lb; }
        }
        __syncthreads();   // Az/Ac reuse safety within the block
    }
}

// ---------------------------------------------------------------------------
// out = relu(ht @ Wlin.T + blin)  (M=256,N=256,K=512 hi/lo) -> fp32
// ---------------------------------------------------------------------------
__global__ __launch_bounds__(256) void k_final(const ushort* __restrict__ ht_hi,
                                               const ushort* __restrict__ ht_lo,
                                               const ushort* __restrict__ Wl_hi,
                                               const ushort* __restrict__ Wl_lo,
                                               const float* __restrict__ blin,
                                               float* __restrict__ out) {
    int tid = threadIdx.x, lane = tid & 63, w = tid >> 6;
    int wm = w & 1, wn = w >> 1, quad = lane >> 4, lr = lane & 15;
    int m0 = blockIdx.y * 64, n0 = blockIdx.x * 64;
    floatx4 acc[2][2] = {};
    for (int k0 = 0; k0 < 512; k0 += 32) {
        short8 ah[2], al[2], bh[2], bl[2];
#pragma unroll
        for (int tn = 0; tn < 2; tn++) {
            int n = n0 + wn * 32 + tn * 16 + lr;
            bh[tn] = ld8(Wl_hi + n * 512 + k0 + quad * 8);
            bl[tn] = ld8(Wl_lo + n * 512 + k0 + quad * 8);
        }
#pragma unroll
        for (int tm = 0; tm < 2; tm++) {
            int r = m0 + wm * 32 + tm * 16 + lr;
            ah[tm] = ld8(ht_hi + r * 512 + k0 + quad * 8);
            al[tm] = ld8(ht_lo + r * 512 + k0 + quad * 8);
        }
#pragma unroll
        for (int tm = 0; tm < 2; tm++)
#pragma unroll
            for (int tn = 0; tn < 2; tn++) mm3(acc[tm][tn], ah[tm], al[tm], bh[tn], bl[tn]);
    }
#pragma unroll
    for (int tm = 0; tm < 2; tm++)
#pragma unroll
        for (int tn = 0; tn < 2; tn++)
#pragma unroll
            for (int r4 = 0; r4 < 4; r4++) {
                int row = m0 + wm * 32 + tm * 16 + quad * 4 + r4;
                int n = n0 + wn * 32 + tn * 16 + lr;
                out[row * 256 + n] = fmaxf(acc[tm][tn][r4] + blin[n], 0.0f);
            }
}

// ---------------------------------------------------------------------------
extern "C" void kernel_launch(void* const* d_in, const int* in_sizes, int n_in,
                              void* d_out, int out_size, void* d_ws, size_t ws_size,
                              hipStream_t stream) {
    (void)in_sizes; (void)n_in; (void)out_size; (void)ws_size;
    const float* y      = (const float*)d_in[0];
    const int*   x      = (const int*)d_in[1];
    const float* emb    = (const float*)d_in[2];
    const float* W_ih   = (const float*)d_in[3];
    const float* W_hh   = (const float*)d_in[4];
    const float* b_ih   = (const float*)d_in[5];
    const float* b_hh   = (const float*)d_in[6];
    const float* W_iht  = (const float*)d_in[7];
    const float* W_hht  = (const float*)d_in[8];
    const float* b_iht  = (const float*)d_in[9];
    const float* b_hht  = (const float*)d_in[10];
    const float* Wg     = (const float*)d_in[11];
    const float* bg     = (const float*)d_in[12];
    const float* Wlin   = (const float*)d_in[13];
    const float* blin   = (const float*)d_in[14];
    const float* u1     = (const float*)d_in[15];
    const float* u2     = (const float*)d_in[16];
    float* out = (float*)d_out;

    // ws layout (uints): flags+claim[4128] hP[131072] htP0[131072] htP1[131072]
    //                    hfP[131072] gy[131072 f32] ht_hi/ht_lo[131072 us] wreg
    uint* bar = (uint*)d_ws;            // gflags = bar (16x16); claim = bar+1024
    uint* hP   = bar + 4128;
    uint* htP0 = hP + 131072;
    uint* htP1 = htP0 + 131072;
    uint* hfP  = htP1 + 131072;
    float* gy  = (float*)(hfP + 131072);
    ushort* ht_hi = (ushort*)(gy + 131072);
    ushort* ht_lo = ht_hi + 131072;
    ushort* wreg  = ht_lo + 131072;

    KP p;
    p.b_ih = b_ih; p.b_hh = b_hh; p.b_iht = b_iht; p.b_hht = b_hht;
    p.u1 = u1; p.u2 = u2; p.gy = gy; p.x = x;
    p.gflags = bar; p.claim = bar + 1024;
    p.hP = hP; p.htP0 = htP0; p.htP1 = htP1; p.hfP = hfP;
    p.ht_hi = ht_hi; p.ht_lo = ht_lo;
    p.Wih_hi  = wreg;             p.Wih_lo  = wreg + 1048576;
    p.Whh_hi  = wreg + 2097152;   p.Whh_lo  = wreg + 3145728;
    p.Wiht_hi = wreg + 4194304;   p.Wiht_lo = wreg + 5242880;
    p.Whht_hi = wreg + 6291456;   p.Whht_lo = wreg + 7340032;
    p.Wg_hi   = wreg + 8388608;   p.Wg_lo   = wreg + 9699328;
    p.em_hi   = wreg + 11272192;  p.em_lo   = wreg + 14450176;
    const ushort* Wl_hi = wreg + 11010048; const ushort* Wl_lo = wreg + 11141120;
    const ushort* y_hi  = wreg + 17628160; const ushort* y_lo  = wreg + 18152448;

    k_prep<<<dim3(38030), dim3(256), 0, stream>>>(W_ih, W_hh, W_iht, W_hht, Wg, Wlin,
                                                  emb, y, wreg, bar);
    k_gy<<<dim3(256), dim3(512), 0, stream>>>(y_hi, y_lo, p.Wg_hi, p.Wg_lo, bg, gy);

    void* args[] = {(void*)&p};
    hipLaunchCooperativeKernel((const void*)k_main, dim3(256), dim3(512), args, 0, stream);

    k_final<<<dim3(4, 4), dim3(256), 0, stream>>>(ht_hi, ht_lo, Wl_hi, Wl_lo, blin, out);
}